// Round 4
// baseline (504.459 us; speedup 1.0000x reference)
//
#include <hip/hip_runtime.h>
#include <hip/hip_bf16.h>
#include <stdint.h>

typedef float f32x4 __attribute__((ext_vector_type(4)));
typedef short s16x8 __attribute__((ext_vector_type(8)));

__device__ __forceinline__ float bf2f(unsigned short u) {
    union { unsigned int i; float f; } v; v.i = ((unsigned int)u) << 16; return v.f;
}
__device__ __forceinline__ unsigned short f2bf(float f) {
    union { float f; unsigned int i; } v; v.f = f;
    unsigned int x = v.i;
    return (unsigned short)((x + 0x7fffu + ((x >> 16) & 1u)) >> 16);
}
__device__ __forceinline__ void gload16(const void* g, void* l) {
    __builtin_amdgcn_global_load_lds(
        (const __attribute__((address_space(1))) void*)g,
        (__attribute__((address_space(3))) void*)l, 16, 0, 0);
}

// ---------------- graph build ----------------
__global__ void k_init_deg(int* deg, int n) {
    int i = blockIdx.x * blockDim.x + threadIdx.x;
    if (i < n) deg[i] = 1;            // self-loop
}

__global__ void k_count(const int* __restrict__ ei, int E, int* deg) {
    int e = blockIdx.x * blockDim.x + threadIdx.x;
    if (e < E) atomicAdd(&deg[ei[E + e]], 1);
}

// single-block scan: thread t owns elements [t*per, t*per+per)
__global__ __launch_bounds__(1024) void k_scan(const int* __restrict__ deg,
                                               int* rowptr, int* wo,
                                               float* dinv, int n) {
    __shared__ int partial[1024];
    int tid = threadIdx.x;
    int per = (n + 1023) >> 10;
    int base = tid * per;
    int end = base + per; if (end > n) end = n;
    int s = 0;
    for (int i = base; i < end; ++i) s += deg[i];
    partial[tid] = s;
    __syncthreads();
    for (int off = 1; off < 1024; off <<= 1) {
        int add = ((int)tid >= off) ? partial[tid - off] : 0;
        __syncthreads();
        partial[tid] += add;
        __syncthreads();
    }
    int run = partial[tid] - s;      // exclusive
    for (int i = base; i < end; ++i) {
        int d = deg[i];
        rowptr[i] = run; wo[i] = run;
        dinv[i] = rsqrtf((float)d);
        run += d;
    }
    if (tid == 1023) rowptr[n] = partial[1023];
}

__global__ void k_fill(const int* __restrict__ ei, int E, int n,
                       int* wo, int* srcs) {
    int e = blockIdx.x * blockDim.x + threadIdx.x;
    int EP = E + n;
    if (e >= EP) return;
    int s_, d_;
    if (e < E) { s_ = ei[e]; d_ = ei[E + e]; }
    else       { s_ = d_ = e - E; }
    int pos = atomicAdd(&wo[d_], 1);
    srcs[pos] = s_;
}

// ---------------- GCN (rank-1): fused sval + outer product ----------------
__global__ __launch_bounds__(256) void k_h0f(const float* __restrict__ x,
                                             const float* __restrict__ dinv,
                                             const int* __restrict__ rowptr,
                                             const int* __restrict__ srcs,
                                             const float* __restrict__ W0,
                                             const float* __restrict__ b0,
                                             float* __restrict__ h,
                                             unsigned short* __restrict__ hbf, int n) {
    int node = blockIdx.x;
    int tid = threadIdx.x;
    if (node >= n) { hbf[(size_t)node * 256 + tid] = 0; return; }
    __shared__ float sv;
    if (tid < 64) {
        int p0 = rowptr[node], p1 = rowptr[node + 1];
        float sum = 0.f;
        for (int p = p0 + tid; p < p1; p += 64) {
            int s = srcs[p];
            sum += x[s] * dinv[s];
        }
#pragma unroll
        for (int m = 1; m < 64; m <<= 1) sum += __shfl_xor(sum, m);
        if (tid == 0) sv = sum * dinv[node];
    }
    __syncthreads();
    float v = fmaxf(sv * W0[tid] + b0[tid], 0.f);
    size_t idx = (size_t)node * 256 + tid;
    h[idx] = v;
    hbf[idx] = f2bf(v);
}

// ---------------- weight prep ----------------
// Wt (per layer, 320 rows x 256 cols): rows 0..255 = W^T; rows 256..319 filled by k_wa.
// lt: 128 rows x 256 cols = lin_W^T.
__global__ void k_wconv(const float* __restrict__ gat_lin,
                        const float* __restrict__ lin_W,
                        unsigned short* __restrict__ Wt,
                        unsigned short* __restrict__ lt) {
    int idx = blockIdx.x * blockDim.x + threadIdx.x;
    const int T1 = 5 * 65536;
    if (idx < T1) {
        int l = idx >> 16, r = idx & 0xFFFF;
        int nrow = r >> 8, k = r & 255;
        Wt[(size_t)l * 81920 + nrow * 256 + k] =
            f2bf(gat_lin[(size_t)l * 65536 + k * 256 + nrow]);
    } else if (idx < T1 + 128 * 256) {
        int j = idx - T1;
        int nrow = j >> 8, k = j & 255;
        lt[nrow * 256 + k] = f2bf(lin_W[(size_t)k * 128 + nrow]);
    }
}

// rows 256..319 of each layer's Wt: 256+head = W@a_src[head], 264+head = W@a_dst[head], rest 0
__global__ void k_wa(const float* __restrict__ gat_lin,
                     const float* __restrict__ att_src,
                     const float* __restrict__ att_dst,
                     unsigned short* __restrict__ Wt) {
    int idx = blockIdx.x * blockDim.x + threadIdx.x;
    if (idx >= 5 * 16384) return;
    int l = idx >> 14, r = idx & 16383;
    int row = r >> 8, k = r & 255;
    float v = 0.f;
    if (row < 16) {
        int head = row & 7;
        const float* a = (row < 8) ? (att_src + l * 256 + head * 32)
                                   : (att_dst + l * 256 + head * 32);
        const float* wr = gat_lin + (size_t)l * 65536 + k * 256 + head * 32;
#pragma unroll
        for (int d = 0; d < 32; ++d) v += wr[d] * a[d];
    }
    Wt[(size_t)l * 81920 + (256 + row) * 256 + k] = f2bf(v);
}

// ---------------- GraphNorm ----------------
__global__ __launch_bounds__(256) void k_gn_reduce(const float* __restrict__ h,
                                                   float* sums, float* sumsq, int n) {
    int f = threadIdx.x;
    float s = 0.f, q = 0.f;
    for (int r = blockIdx.x; r < n; r += gridDim.x) {
        float v = h[(size_t)r * 256 + f];
        s += v; q += v * v;
    }
    atomicAdd(&sums[f], s);
    atomicAdd(&sumsq[f], q);
}

__global__ void k_gn_apply(float* __restrict__ h, unsigned short* __restrict__ hbf,
                           const float* __restrict__ stats,
                           const float* __restrict__ w, const float* __restrict__ b,
                           const float* __restrict__ ms, float ninv) {
    int node = blockIdx.x, f = threadIdx.x;
    float mean = stats[f] * ninv;
    float m2   = stats[256 + f] * ninv;
    float msf  = ms[f];
    float var  = m2 + msf * mean * mean * (msf - 2.0f);
    float scale = w[f] * rsqrtf(var + 1e-5f);
    size_t idx = (size_t)node * 256 + f;
    float v = (h[idx] - msf * mean) * scale + b[f];
    h[idx] = v;
    hbf[idx] = f2bf(v);
}

// ---------------- MFMA GEMM: C[M,N] = A[M,256] @ Bt[N,256]^T ----------------
// Layer GEMMs: Cb=h1 (bf16, cols<256), cols 256..271 -> sbuf/tbuf (f32). Final: Cf+bias.
#define BM 64
#define BN 64
__global__ __launch_bounds__(256) void k_gemm_mfma(
    const unsigned short* __restrict__ A,
    const unsigned short* __restrict__ Bt,
    unsigned short* __restrict__ Cb,
    float* __restrict__ Cf,
    float* __restrict__ sbuf,
    float* __restrict__ tbuf,
    const float* __restrict__ bias,
    int M, int ldc)
{
    __shared__ unsigned short As[64 * 256];
    __shared__ unsigned short Bs[64 * 256];
    const int tid = threadIdx.x;
    const int bm = blockIdx.x * BM, bn = blockIdx.y * BN;
    const char* ga = (const char*)(A + (size_t)bm * 256);
    const char* gb = (const char*)(Bt + (size_t)bn * 256);
    char* la = (char*)As;
    char* lb = (char*)Bs;
#pragma unroll
    for (int i = 0; i < 8; ++i) {
        int o  = (i * 256 + tid) * 16;
        int so = o ^ (((o >> 9) & 7) << 4);
        gload16(ga + so, la + o);
        gload16(gb + so, lb + o);
    }
    __syncthreads();

    const int lane = tid & 63;
    const int w  = tid >> 6;
    const int wm = (w >> 1) * 32, wn = (w & 1) * 32;
    const int r  = lane & 15, kb = lane >> 4;
    f32x4 acc[2][2] = {};
#pragma unroll
    for (int ks = 0; ks < 8; ++ks) {
        s16x8 af[2], bfr[2];
#pragma unroll
        for (int f = 0; f < 2; ++f) {
            int row = wm + f * 16 + r;
            int c16 = (ks * 4 + kb) ^ (row & 7);
            af[f]  = *(const s16x8*)(la + row * 512 + c16 * 16);
            int col = wn + f * 16 + r;
            int d16 = (ks * 4 + kb) ^ (col & 7);
            bfr[f] = *(const s16x8*)(lb + col * 512 + d16 * 16);
        }
#pragma unroll
        for (int i = 0; i < 2; ++i)
#pragma unroll
            for (int j = 0; j < 2; ++j)
                acc[i][j] = __builtin_amdgcn_mfma_f32_16x16x32_bf16(
                    af[i], bfr[j], acc[i][j], 0, 0, 0);
    }

    const int r4 = (lane >> 4) * 4;
    const int cc = lane & 15;
#pragma unroll
    for (int i = 0; i < 2; ++i) {
#pragma unroll
        for (int j = 0; j < 2; ++j) {
            int col = bn + wn + j * 16 + cc;
#pragma unroll
            for (int q = 0; q < 4; ++q) {
                int row = bm + wm + i * 16 + r4 + q;
                float v = acc[i][j][q];
                if (Cb) {
                    if (col < 256) {
                        Cb[(size_t)row * 256 + col] = f2bf(v);
                    } else if (col < 264) {
                        sbuf[(size_t)row * 8 + (col - 256)] = v;
                    } else if (col < 272) {
                        tbuf[(size_t)row * 8 + (col - 264)] = v;
                    }
                } else if (row < M) {
                    Cf[(size_t)row * ldc + col] = v + bias[col];
                }
            }
        }
    }
}

// ------ fused: per-(node,head) online softmax + gather-aggregate + bias/relu/residual ------
__global__ __launch_bounds__(256) void k_fagg(const unsigned short* __restrict__ h1,
                                              const float* __restrict__ sbuf,
                                              const float* __restrict__ tbuf,
                                              const int* __restrict__ rowptr,
                                              const int* __restrict__ srcs,
                                              float* __restrict__ h,
                                              unsigned short* __restrict__ hbf,
                                              const float* __restrict__ bias, int n) {
    int wave = threadIdx.x >> 6, lane = threadIdx.x & 63;
    int node = blockIdx.x * 4 + wave;
    if (node >= n) return;
    int p0 = rowptr[node], p1 = rowptr[node + 1];
    int head = lane >> 3;
    float tv = tbuf[node * 8 + head];
    // pass 1: online max + denom
    float m = -1e30f, den = 0.f;
    for (int p = p0; p < p1; ++p) {
        float e = sbuf[srcs[p] * 8 + head] + tv;
        e = (e > 0.f) ? e : 0.2f * e;
        if (e > m) { den = den * __expf(m - e) + 1.f; m = e; }
        else       { den += __expf(e - m); }
    }
    float inv = 1.0f / (den + 1e-16f);
    // pass 2: weighted gather
    float a0 = 0.f, a1 = 0.f, a2 = 0.f, a3 = 0.f;
    for (int p = p0; p < p1; ++p) {
        int src = srcs[p];
        float e = sbuf[src * 8 + head] + tv;
        e = (e > 0.f) ? e : 0.2f * e;
        float al = __expf(e - m) * inv;
        ushort4 v = reinterpret_cast<const ushort4*>(h1 + (size_t)src * 256)[lane];
        a0 += al * bf2f(v.x); a1 += al * bf2f(v.y);
        a2 += al * bf2f(v.z); a3 += al * bf2f(v.w);
    }
    float b0_ = 0.f, b1_ = 0.f, b2_ = 0.f, b3_ = 0.f;
    if (bias) {
        float4 bb = reinterpret_cast<const float4*>(bias)[lane];
        b0_ = bb.x; b1_ = bb.y; b2_ = bb.z; b3_ = bb.w;
    }
    size_t base = (size_t)node * 256 + lane * 4;
    float4 hv = *reinterpret_cast<float4*>(h + base);
    hv.x += fmaxf(a0 + b0_, 0.f);
    hv.y += fmaxf(a1 + b1_, 0.f);
    hv.z += fmaxf(a2 + b2_, 0.f);
    hv.w += fmaxf(a3 + b3_, 0.f);
    *reinterpret_cast<float4*>(h + base) = hv;
    ushort4 o;
    o.x = f2bf(hv.x); o.y = f2bf(hv.y); o.z = f2bf(hv.z); o.w = f2bf(hv.w);
    *reinterpret_cast<ushort4*>(hbf + base) = o;
}

// ---------------- launch ----------------
extern "C" void kernel_launch(void* const* d_in, const int* in_sizes, int n_in,
                              void* d_out, int out_size, void* d_ws, size_t ws_size,
                              hipStream_t stream) {
    const float* x        = (const float*)d_in[0];
    const float* W0       = (const float*)d_in[1];
    const float* b0       = (const float*)d_in[2];
    const float* gat_lin  = (const float*)d_in[3];
    const float* att_src  = (const float*)d_in[4];
    const float* att_dst  = (const float*)d_in[5];
    const float* gat_bias = (const float*)d_in[6];
    const float* gn_w     = (const float*)d_in[7];
    const float* gn_b     = (const float*)d_in[8];
    const float* gn_ms    = (const float*)d_in[9];
    const float* lin_W    = (const float*)d_in[10];
    const float* lin_b    = (const float*)d_in[11];
    const int*   ei       = (const int*)d_in[12];

    const int n  = in_sizes[0];          // 20000
    const int E  = in_sizes[12] / 2;     // 160000
    const int EP = E + n;                // 180000
    const int Mpad = ((n + BM - 1) / BM) * BM;   // 20032

    // workspace layout (16B-aligned chunks)
    char* w = (char*)d_ws;
    float* h    = (float*)w;                  w += (size_t)Mpad * 256 * 4;
    unsigned short* hbf = (unsigned short*)w; w += (size_t)Mpad * 256 * 2;
    unsigned short* h1  = (unsigned short*)w; w += (size_t)Mpad * 256 * 2;
    float* sbuf = (float*)w;                  w += (size_t)Mpad * 8 * 4;
    float* tbuf = (float*)w;                  w += (size_t)Mpad * 8 * 4;
    unsigned short* Wt = (unsigned short*)w;  w += (size_t)5 * 320 * 256 * 2;
    unsigned short* lt = (unsigned short*)w;  w += (size_t)128 * 256 * 2;
    float* gnstat = (float*)w;                w += 1024 * 4;
    float* dinv = (float*)w;                  w += (size_t)n * 4;
    int* deg    = (int*)w;                    w += (size_t)n * 4;
    int* rowptr = (int*)w;                    w += ((size_t)(n + 1) * 4 + 15) / 16 * 16;
    int* wo     = (int*)w;                    w += (size_t)n * 4;
    int* srcs   = (int*)w;                    w += (size_t)EP * 4;

    const int B256 = 256;
    auto cdiv = [](int a, int b) { return (a + b - 1) / b; };

    hipMemsetAsync(gnstat, 0, 1024 * 4, stream);

    // weight prep
    k_wconv<<<cdiv(5 * 65536 + 128 * 256, B256), B256, 0, stream>>>(gat_lin, lin_W, Wt, lt);
    k_wa<<<cdiv(5 * 16384, B256), B256, 0, stream>>>(gat_lin, att_src, att_dst, Wt);

    // graph build
    k_init_deg<<<cdiv(n, B256), B256, 0, stream>>>(deg, n);
    k_count<<<cdiv(E, B256), B256, 0, stream>>>(ei, E, deg);
    k_scan<<<1, 1024, 0, stream>>>(deg, rowptr, wo, dinv, n);
    k_fill<<<cdiv(EP, B256), B256, 0, stream>>>(ei, E, n, wo, srcs);

    // GCN layer (rank-1, fused)
    k_h0f<<<Mpad, 256, 0, stream>>>(x, dinv, rowptr, srcs, W0, b0, h, hbf, n);

    const float ninv = 1.0f / (float)n;
    const int gx = Mpad / BM;   // 313

    for (int i = 0; i < 5; ++i) {
        if (i % 3 == 0) {
            int g = i / 3;
            k_gn_reduce<<<256, 256, 0, stream>>>(h, gnstat + g * 512,
                                                 gnstat + g * 512 + 256, n);
            k_gn_apply<<<n, 256, 0, stream>>>(h, hbf, gnstat + g * 512,
                                              gn_w + g * 256, gn_b + g * 256,
                                              gn_ms + g * 256, ninv);
        }
        k_gemm_mfma<<<dim3(gx, 5), 256, 0, stream>>>(
            hbf, Wt + (size_t)i * 81920, h1, nullptr, sbuf, tbuf, nullptr, n, 256);
        k_fagg<<<cdiv(n, 4), 256, 0, stream>>>(
            h1, sbuf, tbuf, rowptr, srcs, h, hbf,
            (i % 3 == 0) ? gat_bias + i * 256 : nullptr, n);
    }

    // final linear -> d_out (fp32, guarded, +bias)
    k_gemm_mfma<<<dim3(gx, 2), 256, 0, stream>>>(
        hbf, lt, nullptr, (float*)d_out, nullptr, nullptr, lin_b, n, 128);
}

// Round 5
// 396.442 us; speedup vs baseline: 1.2725x; 1.2725x over previous
//
#include <hip/hip_runtime.h>
#include <hip/hip_bf16.h>
#include <stdint.h>

typedef float f32x4 __attribute__((ext_vector_type(4)));
typedef short s16x8 __attribute__((ext_vector_type(8)));

__device__ __forceinline__ float bf2f(unsigned short u) {
    union { unsigned int i; float f; } v; v.i = ((unsigned int)u) << 16; return v.f;
}
__device__ __forceinline__ unsigned short f2bf(float f) {
    union { float f; unsigned int i; } v; v.f = f;
    unsigned int x = v.i;
    return (unsigned short)((x + 0x7fffu + ((x >> 16) & 1u)) >> 16);
}
__device__ __forceinline__ void gload16(const void* g, void* l) {
    __builtin_amdgcn_global_load_lds(
        (const __attribute__((address_space(1))) void*)g,
        (__attribute__((address_space(3))) void*)l, 16, 0, 0);
}

// ---------------- graph build ----------------
__global__ void k_init_deg(int* deg, int n) {
    int i = blockIdx.x * blockDim.x + threadIdx.x;
    if (i < n) deg[i] = 1;            // self-loop
}

__global__ void k_count(const int* __restrict__ ei, int E, int* deg) {
    int e = blockIdx.x * blockDim.x + threadIdx.x;
    if (e < E) atomicAdd(&deg[ei[E + e]], 1);
}

// single-block scan: thread t owns elements [t*per, t*per+per)
__global__ __launch_bounds__(1024) void k_scan(const int* __restrict__ deg,
                                               int* rowptr, int* wo,
                                               float* dinv, int n) {
    __shared__ int partial[1024];
    int tid = threadIdx.x;
    int per = (n + 1023) >> 10;
    int base = tid * per;
    int end = base + per; if (end > n) end = n;
    int s = 0;
    for (int i = base; i < end; ++i) s += deg[i];
    partial[tid] = s;
    __syncthreads();
    for (int off = 1; off < 1024; off <<= 1) {
        int add = ((int)tid >= off) ? partial[tid - off] : 0;
        __syncthreads();
        partial[tid] += add;
        __syncthreads();
    }
    int run = partial[tid] - s;      // exclusive
    for (int i = base; i < end; ++i) {
        int d = deg[i];
        rowptr[i] = run; wo[i] = run;
        dinv[i] = rsqrtf((float)d);
        run += d;
    }
    if (tid == 1023) rowptr[n] = partial[1023];
}

__global__ void k_fill(const int* __restrict__ ei, int E, int n,
                       int* wo, int* srcs) {
    int e = blockIdx.x * blockDim.x + threadIdx.x;
    int EP = E + n;
    if (e >= EP) return;
    int s_, d_;
    if (e < E) { s_ = ei[e]; d_ = ei[E + e]; }
    else       { s_ = d_ = e - E; }
    int pos = atomicAdd(&wo[d_], 1);
    srcs[pos] = s_;
}

// ---------------- GCN (rank-1): fused sval + outer product ----------------
__global__ __launch_bounds__(256) void k_h0f(const float* __restrict__ x,
                                             const float* __restrict__ dinv,
                                             const int* __restrict__ rowptr,
                                             const int* __restrict__ srcs,
                                             const float* __restrict__ W0,
                                             const float* __restrict__ b0,
                                             unsigned short* __restrict__ hbf, int n) {
    int node = blockIdx.x;
    int tid = threadIdx.x;
    if (node >= n) { hbf[(size_t)node * 256 + tid] = 0; return; }
    __shared__ float sv;
    if (tid < 64) {
        int p0 = rowptr[node], p1 = rowptr[node + 1];
        float sum = 0.f;
        for (int p = p0 + tid; p < p1; p += 64) {
            int s = srcs[p];
            sum += x[s] * dinv[s];
        }
#pragma unroll
        for (int m = 1; m < 64; m <<= 1) sum += __shfl_xor(sum, m);
        if (tid == 0) sv = sum * dinv[node];
    }
    __syncthreads();
    float v = fmaxf(sv * W0[tid] + b0[tid], 0.f);
    hbf[(size_t)node * 256 + tid] = f2bf(v);
}

// ---------------- weight prep (single kernel) ----------------
// Wt per layer: 320 rows x 256 cols bf16. rows 0..255 = W^T;
// rows 256..263 = W@a_src[head]; 264..271 = W@a_dst[head]; 272..319 = 0.
// lt: 128 rows x 256 cols = lin_W^T.
__global__ void k_wprep(const float* __restrict__ gat_lin,
                        const float* __restrict__ lin_W,
                        const float* __restrict__ att_src,
                        const float* __restrict__ att_dst,
                        unsigned short* __restrict__ Wt,
                        unsigned short* __restrict__ lt) {
    int idx = blockIdx.x * blockDim.x + threadIdx.x;
    const int T1 = 5 * 65536;            // W^T entries
    const int T2 = T1 + 128 * 256;       // + lt entries
    const int T3 = T2 + 5 * 64 * 256;    // + extra rows
    if (idx < T1) {
        int l = idx >> 16, r = idx & 0xFFFF;
        int nrow = r >> 8, k = r & 255;
        Wt[(size_t)l * 81920 + nrow * 256 + k] =
            f2bf(gat_lin[(size_t)l * 65536 + k * 256 + nrow]);
    } else if (idx < T2) {
        int j = idx - T1;
        int nrow = j >> 8, k = j & 255;
        lt[nrow * 256 + k] = f2bf(lin_W[(size_t)k * 128 + nrow]);
    } else if (idx < T3) {
        int j = idx - T2;
        int l = j >> 14, r = j & 16383;
        int row = r >> 8, k = r & 255;
        float v = 0.f;
        if (row < 16) {
            int head = row & 7;
            const float* a = (row < 8) ? (att_src + l * 256 + head * 32)
                                       : (att_dst + l * 256 + head * 32);
            const float* wr = gat_lin + (size_t)l * 65536 + k * 256 + head * 32;
#pragma unroll
            for (int d = 0; d < 32; ++d) v += wr[d] * a[d];
        }
        Wt[(size_t)l * 81920 + (256 + row) * 256 + k] = f2bf(v);
    }
}

// ---------------- GraphNorm (bf16 stream) ----------------
__global__ __launch_bounds__(256) void k_gn_reduce(const unsigned short* __restrict__ hbf,
                                                   float* sums, float* sumsq, int n) {
    int f = threadIdx.x;
    float s = 0.f, q = 0.f;
    for (int r = blockIdx.x; r < n; r += gridDim.x) {
        float v = bf2f(hbf[(size_t)r * 256 + f]);
        s += v; q += v * v;
    }
    atomicAdd(&sums[f], s);
    atomicAdd(&sumsq[f], q);
}

__global__ void k_gn_apply(unsigned short* __restrict__ hbf,
                           const float* __restrict__ stats,
                           const float* __restrict__ w, const float* __restrict__ b,
                           const float* __restrict__ ms, float ninv) {
    int node = blockIdx.x, f = threadIdx.x;
    float mean = stats[f] * ninv;
    float m2   = stats[256 + f] * ninv;
    float msf  = ms[f];
    float var  = m2 + msf * mean * mean * (msf - 2.0f);
    float scale = w[f] * rsqrtf(var + 1e-5f);
    size_t idx = (size_t)node * 256 + f;
    float v = (bf2f(hbf[idx]) - msf * mean) * scale + b[f];
    hbf[idx] = f2bf(v);
}

// ---------------- MFMA GEMM with A-reuse: C[M,*] = A[M,256] @ Bt[*,256]^T ----------------
// 512 threads (8 waves). Block stages 64-row A tile once, loops over 64-col B panels
// (double-buffered). Layer GEMM: panels 0..4 (N=320), cols<256 -> Cb bf16,
// 256..263 -> sbuf, 264..271 -> tbuf. Final: Cf fp32 + bias, guarded rows.
#define BM 64
__global__ __launch_bounds__(512) void k_gemm_mfma(
    const unsigned short* __restrict__ A,
    const unsigned short* __restrict__ Bt,
    unsigned short* __restrict__ Cb,
    float* __restrict__ Cf,
    float* __restrict__ sbuf,
    float* __restrict__ tbuf,
    const float* __restrict__ bias,
    int M, int ldc, int nbTot, int nbPerY)
{
    __shared__ unsigned short As[64 * 256];        // 32 KB
    __shared__ unsigned short Bs[2][64 * 256];     // 64 KB
    const int tid = threadIdx.x;
    const int bm = blockIdx.x * BM;
    const int nb0 = blockIdx.y * nbPerY;
    int nb1 = nb0 + nbPerY; if (nb1 > nbTot) nb1 = nbTot;

    {   // stage A (32 KB) + first B panel (32 KB)
        const char* ga = (const char*)(A + (size_t)bm * 256);
        const char* gb = (const char*)(Bt + (size_t)nb0 * 16384);
        char* la = (char*)As;
        char* lb = (char*)Bs[0];
#pragma unroll
        for (int i = 0; i < 4; ++i) {
            int o  = (i * 512 + tid) * 16;
            int so = o ^ (((o >> 9) & 7) << 4);
            gload16(ga + so, la + o);
            gload16(gb + so, lb + o);
        }
    }
    __syncthreads();

    const int lane = tid & 63;
    const int w  = tid >> 6;                  // 0..7
    const int wm = (w >> 1) * 16;             // 0,16,32,48
    const int wn = (w & 1) * 32;              // 0,32
    const int r  = lane & 15, kb = lane >> 4;
    const int r4 = (lane >> 4) * 4, cc = lane & 15;
    const char* la = (const char*)As;

    for (int nb = nb0; nb < nb1; ++nb) {
        int cur = (nb - nb0) & 1;
        if (nb + 1 < nb1) {                   // prefetch next panel
            const char* gb = (const char*)(Bt + (size_t)(nb + 1) * 16384);
            char* lb = (char*)Bs[cur ^ 1];
#pragma unroll
            for (int i = 0; i < 4; ++i) {
                int o  = (i * 512 + tid) * 16;
                int so = o ^ (((o >> 9) & 7) << 4);
                gload16(gb + so, lb + o);
            }
        }
        const char* lb = (const char*)Bs[cur];
        f32x4 acc[2] = {};
#pragma unroll
        for (int ks = 0; ks < 8; ++ks) {
            int row = wm + r;
            int c16 = (ks * 4 + kb) ^ (row & 7);
            s16x8 af = *(const s16x8*)(la + row * 512 + c16 * 16);
#pragma unroll
            for (int j = 0; j < 2; ++j) {
                int col = wn + j * 16 + r;
                int d16 = (ks * 4 + kb) ^ (col & 7);
                s16x8 bfr = *(const s16x8*)(lb + col * 512 + d16 * 16);
                acc[j] = __builtin_amdgcn_mfma_f32_16x16x32_bf16(af, bfr, acc[j], 0, 0, 0);
            }
        }
        // epilogue for this panel
#pragma unroll
        for (int j = 0; j < 2; ++j) {
            int col = nb * 64 + wn + j * 16 + cc;
#pragma unroll
            for (int q = 0; q < 4; ++q) {
                int row = bm + wm + r4 + q;
                float v = acc[j][q];
                if (Cb) {
                    if (col < 256) {
                        Cb[(size_t)row * 256 + col] = f2bf(v);
                    } else if (col < 264) {
                        sbuf[(size_t)row * 8 + (col - 256)] = v;
                    } else if (col < 272) {
                        tbuf[(size_t)row * 8 + (col - 264)] = v;
                    }
                } else if (row < M) {
                    Cf[(size_t)row * ldc + col] = v + bias[col];
                }
            }
        }
        __syncthreads();
    }
}

// ------ fused: per-(node,head) softmax + gather-aggregate + bias/relu/residual (bf16 h) ------
__global__ __launch_bounds__(256) void k_fagg(const unsigned short* __restrict__ h1,
                                              const float* __restrict__ sbuf,
                                              const float* __restrict__ tbuf,
                                              const int* __restrict__ rowptr,
                                              const int* __restrict__ srcs,
                                              unsigned short* __restrict__ hbf,
                                              const float* __restrict__ bias, int n) {
    int wave = threadIdx.x >> 6, lane = threadIdx.x & 63;
    int node = blockIdx.x * 4 + wave;
    if (node >= n) return;
    int p0 = rowptr[node], p1 = rowptr[node + 1];
    int head = lane >> 3;
    float tv = tbuf[node * 8 + head];
    // pass 1: max over raw s (leaky-relu monotone -> fold tv+lrelu once), unroll 4
    float m = -1e30f;
    int p = p0;
    for (; p + 3 < p1; p += 4) {
        float e0 = sbuf[srcs[p]     * 8 + head];
        float e1 = sbuf[srcs[p + 1] * 8 + head];
        float e2 = sbuf[srcs[p + 2] * 8 + head];
        float e3 = sbuf[srcs[p + 3] * 8 + head];
        m = fmaxf(m, fmaxf(fmaxf(e0, e1), fmaxf(e2, e3)));
    }
    for (; p < p1; ++p) m = fmaxf(m, sbuf[srcs[p] * 8 + head]);
    m += tv;
    m = (m > 0.f) ? m : 0.2f * m;
    // pass 2: gather with fused numerator+denominator, unroll 2
    float den = 1e-16f;
    float a0 = 0.f, a1 = 0.f, a2 = 0.f, a3 = 0.f;
    float c0 = 0.f, c1 = 0.f, c2 = 0.f, c3 = 0.f;
    p = p0;
    for (; p + 1 < p1; p += 2) {
        int s0 = srcs[p], s1 = srcs[p + 1];
        float e0 = sbuf[s0 * 8 + head] + tv;
        float e1 = sbuf[s1 * 8 + head] + tv;
        e0 = (e0 > 0.f) ? e0 : 0.2f * e0;
        e1 = (e1 > 0.f) ? e1 : 0.2f * e1;
        float w0 = __expf(e0 - m), w1 = __expf(e1 - m);
        ushort4 v0 = reinterpret_cast<const ushort4*>(h1 + (size_t)s0 * 256)[lane];
        ushort4 v1 = reinterpret_cast<const ushort4*>(h1 + (size_t)s1 * 256)[lane];
        den += w0 + w1;
        a0 += w0 * bf2f(v0.x); a1 += w0 * bf2f(v0.y);
        a2 += w0 * bf2f(v0.z); a3 += w0 * bf2f(v0.w);
        c0 += w1 * bf2f(v1.x); c1 += w1 * bf2f(v1.y);
        c2 += w1 * bf2f(v1.z); c3 += w1 * bf2f(v1.w);
    }
    if (p < p1) {
        int s0 = srcs[p];
        float e0 = sbuf[s0 * 8 + head] + tv;
        e0 = (e0 > 0.f) ? e0 : 0.2f * e0;
        float w0 = __expf(e0 - m);
        ushort4 v0 = reinterpret_cast<const ushort4*>(h1 + (size_t)s0 * 256)[lane];
        den += w0;
        a0 += w0 * bf2f(v0.x); a1 += w0 * bf2f(v0.y);
        a2 += w0 * bf2f(v0.z); a3 += w0 * bf2f(v0.w);
    }
    float inv = 1.0f / den;
    a0 = (a0 + c0) * inv; a1 = (a1 + c1) * inv;
    a2 = (a2 + c2) * inv; a3 = (a3 + c3) * inv;
    float b0_ = 0.f, b1_ = 0.f, b2_ = 0.f, b3_ = 0.f;
    if (bias) {
        float4 bb = reinterpret_cast<const float4*>(bias)[lane];
        b0_ = bb.x; b1_ = bb.y; b2_ = bb.z; b3_ = bb.w;
    }
    size_t base = (size_t)node * 256 + lane * 4;
    ushort4 hv = *reinterpret_cast<const ushort4*>(hbf + base);
    ushort4 o;
    o.x = f2bf(bf2f(hv.x) + fmaxf(a0 + b0_, 0.f));
    o.y = f2bf(bf2f(hv.y) + fmaxf(a1 + b1_, 0.f));
    o.z = f2bf(bf2f(hv.z) + fmaxf(a2 + b2_, 0.f));
    o.w = f2bf(bf2f(hv.w) + fmaxf(a3 + b3_, 0.f));
    *reinterpret_cast<ushort4*>(hbf + base) = o;
}

// ---------------- launch ----------------
extern "C" void kernel_launch(void* const* d_in, const int* in_sizes, int n_in,
                              void* d_out, int out_size, void* d_ws, size_t ws_size,
                              hipStream_t stream) {
    const float* x        = (const float*)d_in[0];
    const float* W0       = (const float*)d_in[1];
    const float* b0       = (const float*)d_in[2];
    const float* gat_lin  = (const float*)d_in[3];
    const float* att_src  = (const float*)d_in[4];
    const float* att_dst  = (const float*)d_in[5];
    const float* gat_bias = (const float*)d_in[6];
    const float* gn_w     = (const float*)d_in[7];
    const float* gn_b     = (const float*)d_in[8];
    const float* gn_ms    = (const float*)d_in[9];
    const float* lin_W    = (const float*)d_in[10];
    const float* lin_b    = (const float*)d_in[11];
    const int*   ei       = (const int*)d_in[12];

    const int n  = in_sizes[0];          // 20000
    const int E  = in_sizes[12] / 2;     // 160000
    const int EP = E + n;                // 180000
    const int Mpad = ((n + BM - 1) / BM) * BM;   // 20032

    // workspace layout (16B-aligned chunks)
    char* w = (char*)d_ws;
    unsigned short* hbf = (unsigned short*)w; w += (size_t)Mpad * 256 * 2;
    unsigned short* h1  = (unsigned short*)w; w += (size_t)Mpad * 256 * 2;
    float* sbuf = (float*)w;                  w += (size_t)Mpad * 8 * 4;
    float* tbuf = (float*)w;                  w += (size_t)Mpad * 8 * 4;
    unsigned short* Wt = (unsigned short*)w;  w += (size_t)5 * 320 * 256 * 2;
    unsigned short* lt = (unsigned short*)w;  w += (size_t)128 * 256 * 2;
    float* gnstat = (float*)w;                w += 1024 * 4;
    float* dinv = (float*)w;                  w += (size_t)n * 4;
    int* deg    = (int*)w;                    w += (size_t)n * 4;
    int* rowptr = (int*)w;                    w += ((size_t)(n + 1) * 4 + 15) / 16 * 16;
    int* wo     = (int*)w;                    w += (size_t)n * 4;
    int* srcs   = (int*)w;                    w += (size_t)EP * 4;

    const int B256 = 256;
    auto cdiv = [](int a, int b) { return (a + b - 1) / b; };

    hipMemsetAsync(gnstat, 0, 1024 * 4, stream);

    // weight prep
    const int WPREP = 5 * 65536 + 128 * 256 + 5 * 64 * 256;
    k_wprep<<<cdiv(WPREP, B256), B256, 0, stream>>>(gat_lin, lin_W, att_src, att_dst, Wt, lt);

    // graph build
    k_init_deg<<<cdiv(n, B256), B256, 0, stream>>>(deg, n);
    k_count<<<cdiv(E, B256), B256, 0, stream>>>(ei, E, deg);
    k_scan<<<1, 1024, 0, stream>>>(deg, rowptr, wo, dinv, n);
    k_fill<<<cdiv(EP, B256), B256, 0, stream>>>(ei, E, n, wo, srcs);

    // GCN layer (rank-1, fused)
    k_h0f<<<Mpad, 256, 0, stream>>>(x, dinv, rowptr, srcs, W0, b0, hbf, n);

    const float ninv = 1.0f / (float)n;
    const int gx = Mpad / BM;   // 313

    for (int i = 0; i < 5; ++i) {
        if (i % 3 == 0) {
            int g = i / 3;
            k_gn_reduce<<<256, 256, 0, stream>>>(hbf, gnstat + g * 512,
                                                 gnstat + g * 512 + 256, n);
            k_gn_apply<<<n, 256, 0, stream>>>(hbf, gnstat + g * 512,
                                              gn_w + g * 256, gn_b + g * 256,
                                              gn_ms + g * 256, ninv);
        }
        // N=320 in 5 panels, split 3+2 across grid.y
        k_gemm_mfma<<<dim3(gx, 2), 512, 0, stream>>>(
            hbf, Wt + (size_t)i * 81920, h1, nullptr, sbuf, tbuf, nullptr, n, 256, 5, 3);
        k_fagg<<<cdiv(n, 4), 256, 0, stream>>>(
            h1, sbuf, tbuf, rowptr, srcs, hbf,
            (i % 3 == 0) ? gat_bias + i * 256 : nullptr, n);
    }

    // final linear -> d_out (fp32, guarded, +bias), N=128 in 2 panels
    k_gemm_mfma<<<dim3(gx, 1), 512, 0, stream>>>(
        hbf, lt, nullptr, (float*)d_out, nullptr, nullptr, lin_b, n, 128, 2, 2);
}

// Round 6
// 349.972 us; speedup vs baseline: 1.4414x; 1.1328x over previous
//
#include <hip/hip_runtime.h>
#include <hip/hip_bf16.h>
#include <stdint.h>

typedef float f32x4 __attribute__((ext_vector_type(4)));
typedef short s16x8 __attribute__((ext_vector_type(8)));

__device__ __forceinline__ float bf2f(unsigned short u) {
    union { unsigned int i; float f; } v; v.i = ((unsigned int)u) << 16; return v.f;
}
__device__ __forceinline__ unsigned short f2bf(float f) {
    union { float f; unsigned int i; } v; v.f = f;
    unsigned int x = v.i;
    return (unsigned short)((x + 0x7fffu + ((x >> 16) & 1u)) >> 16);
}
__device__ __forceinline__ void gload16(const void* g, void* l) {
    __builtin_amdgcn_global_load_lds(
        (const __attribute__((address_space(1))) void*)g,
        (__attribute__((address_space(3))) void*)l, 16, 0, 0);
}

// ---------------- graph build ----------------
__global__ void k_init_deg(int* deg, int n) {
    int i = blockIdx.x * blockDim.x + threadIdx.x;
    if (i < n) deg[i] = 1;            // self-loop
}

__global__ void k_count(const int* __restrict__ ei, int E, int* deg) {
    int e = blockIdx.x * blockDim.x + threadIdx.x;
    if (e < E) atomicAdd(&deg[ei[E + e]], 1);
}

// two-level scan, all parallel/coalesced
__global__ __launch_bounds__(256) void k_bsum(const int* __restrict__ deg,
                                              int* __restrict__ bsum, int n) {
    __shared__ int buf[256];
    int i = blockIdx.x * 256 + threadIdx.x;
    buf[threadIdx.x] = (i < n) ? deg[i] : 0;
    __syncthreads();
#pragma unroll
    for (int off = 128; off > 0; off >>= 1) {
        if ((int)threadIdx.x < off) buf[threadIdx.x] += buf[threadIdx.x + off];
        __syncthreads();
    }
    if (threadIdx.x == 0) bsum[blockIdx.x] = buf[0];
}

__global__ __launch_bounds__(256) void k_scanb(const int* __restrict__ bsum,
                                               int* __restrict__ boff, int nb) {
    __shared__ int buf[256];
    int t = threadIdx.x;
    int v = (t < nb) ? bsum[t] : 0;
    buf[t] = v;
    __syncthreads();
    for (int off = 1; off < 256; off <<= 1) {
        int add = (t >= off) ? buf[t - off] : 0;
        __syncthreads();
        buf[t] += add;
        __syncthreads();
    }
    if (t < nb) boff[t] = buf[t] - v;   // exclusive
}

__global__ __launch_bounds__(256) void k_emit(const int* __restrict__ deg,
                                              const int* __restrict__ boff,
                                              int* __restrict__ rowptr,
                                              int* __restrict__ wo,
                                              float* __restrict__ dinv, int n) {
    __shared__ int buf[256];
    int i = blockIdx.x * 256 + threadIdx.x;
    int v = (i < n) ? deg[i] : 0;
    buf[threadIdx.x] = v;
    __syncthreads();
    for (int off = 1; off < 256; off <<= 1) {
        int add = ((int)threadIdx.x >= off) ? buf[threadIdx.x - off] : 0;
        __syncthreads();
        buf[threadIdx.x] += add;
        __syncthreads();
    }
    if (i < n) {
        int excl = boff[blockIdx.x] + buf[threadIdx.x] - v;
        rowptr[i] = excl;
        wo[i] = excl;
        dinv[i] = rsqrtf((float)v);
        if (i == n - 1) rowptr[n] = excl + v;
    }
}

__global__ void k_fill(const int* __restrict__ ei, int E, int n,
                       int* wo, int* srcs) {
    int e = blockIdx.x * blockDim.x + threadIdx.x;
    int EP = E + n;
    if (e >= EP) return;
    int s_, d_;
    if (e < E) { s_ = ei[e]; d_ = ei[E + e]; }
    else       { s_ = d_ = e - E; }
    int pos = atomicAdd(&wo[d_], 1);
    srcs[pos] = s_;
}

// ---------------- GCN (rank-1): fused sval + outer product ----------------
__global__ __launch_bounds__(256) void k_h0f(const float* __restrict__ x,
                                             const float* __restrict__ dinv,
                                             const int* __restrict__ rowptr,
                                             const int* __restrict__ srcs,
                                             const float* __restrict__ W0,
                                             const float* __restrict__ b0,
                                             unsigned short* __restrict__ hbf, int n) {
    int node = blockIdx.x;
    int tid = threadIdx.x;
    if (node >= n) { hbf[(size_t)node * 256 + tid] = 0; return; }
    __shared__ float sv;
    if (tid < 64) {
        int p0 = rowptr[node], p1 = rowptr[node + 1];
        float sum = 0.f;
        for (int p = p0 + tid; p < p1; p += 64) {
            int s = srcs[p];
            sum += x[s] * dinv[s];
        }
#pragma unroll
        for (int m = 1; m < 64; m <<= 1) sum += __shfl_xor(sum, m);
        if (tid == 0) sv = sum * dinv[node];
    }
    __syncthreads();
    float v = fmaxf(sv * W0[tid] + b0[tid], 0.f);
    hbf[(size_t)node * 256 + tid] = f2bf(v);
}

// ---------------- weight prep (single kernel) ----------------
// Wt per layer: 320 rows x 256 cols bf16. rows 0..255 = W^T;
// rows 256..263 = W@a_src[head]; 264..271 = W@a_dst[head]; 272..319 = 0.
// lt: 128 rows x 256 cols = lin_W^T.
__global__ void k_wprep(const float* __restrict__ gat_lin,
                        const float* __restrict__ lin_W,
                        const float* __restrict__ att_src,
                        const float* __restrict__ att_dst,
                        unsigned short* __restrict__ Wt,
                        unsigned short* __restrict__ lt) {
    int idx = blockIdx.x * blockDim.x + threadIdx.x;
    const int T1 = 5 * 65536;            // W^T entries
    const int T2 = T1 + 128 * 256;       // + lt entries
    const int T3 = T2 + 5 * 64 * 256;    // + extra rows
    if (idx < T1) {
        int l = idx >> 16, r = idx & 0xFFFF;
        int nrow = r >> 8, k = r & 255;
        Wt[(size_t)l * 81920 + nrow * 256 + k] =
            f2bf(gat_lin[(size_t)l * 65536 + k * 256 + nrow]);
    } else if (idx < T2) {
        int j = idx - T1;
        int nrow = j >> 8, k = j & 255;
        lt[nrow * 256 + k] = f2bf(lin_W[(size_t)k * 128 + nrow]);
    } else if (idx < T3) {
        int j = idx - T2;
        int l = j >> 14, r = j & 16383;
        int row = r >> 8, k = r & 255;
        float v = 0.f;
        if (row < 16) {
            int head = row & 7;
            const float* a = (row < 8) ? (att_src + l * 256 + head * 32)
                                       : (att_dst + l * 256 + head * 32);
            const float* wr = gat_lin + (size_t)l * 65536 + k * 256 + head * 32;
#pragma unroll
            for (int d = 0; d < 32; ++d) v += wr[d] * a[d];
        }
        Wt[(size_t)l * 81920 + (256 + row) * 256 + k] = f2bf(v);
    }
}

// ---------------- GraphNorm (bf16 stream) ----------------
__global__ __launch_bounds__(256) void k_gn_reduce(const unsigned short* __restrict__ hbf,
                                                   float* sums, float* sumsq, int n) {
    int f = threadIdx.x;
    float s = 0.f, q = 0.f;
    for (int r = blockIdx.x; r < n; r += gridDim.x) {
        float v = bf2f(hbf[(size_t)r * 256 + f]);
        s += v; q += v * v;
    }
    atomicAdd(&sums[f], s);
    atomicAdd(&sumsq[f], q);
}

__global__ void k_gn_apply(unsigned short* __restrict__ hbf,
                           const float* __restrict__ stats,
                           const float* __restrict__ w, const float* __restrict__ b,
                           const float* __restrict__ ms, float ninv) {
    int node = blockIdx.x, f = threadIdx.x;
    float mean = stats[f] * ninv;
    float m2   = stats[256 + f] * ninv;
    float msf  = ms[f];
    float var  = m2 + msf * mean * mean * (msf - 2.0f);
    float scale = w[f] * rsqrtf(var + 1e-5f);
    size_t idx = (size_t)node * 256 + f;
    float v = (bf2f(hbf[idx]) - msf * mean) * scale + b[f];
    hbf[idx] = f2bf(v);
}

// ---------------- MFMA GEMM with A-reuse: C[M,*] = A[M,256] @ Bt[*,256]^T ----------------
#define BM 64
__global__ __launch_bounds__(512) void k_gemm_mfma(
    const unsigned short* __restrict__ A,
    const unsigned short* __restrict__ Bt,
    unsigned short* __restrict__ Cb,
    float* __restrict__ Cf,
    float* __restrict__ sbuf,
    float* __restrict__ tbuf,
    const float* __restrict__ bias,
    int M, int ldc, int nbTot, int nbPerY)
{
    __shared__ unsigned short As[64 * 256];        // 32 KB
    __shared__ unsigned short Bs[2][64 * 256];     // 64 KB
    const int tid = threadIdx.x;
    const int bm = blockIdx.x * BM;
    const int nb0 = blockIdx.y * nbPerY;
    int nb1 = nb0 + nbPerY; if (nb1 > nbTot) nb1 = nbTot;

    {   // stage A (32 KB) + first B panel (32 KB)
        const char* ga = (const char*)(A + (size_t)bm * 256);
        const char* gb = (const char*)(Bt + (size_t)nb0 * 16384);
        char* la = (char*)As;
        char* lb = (char*)Bs[0];
#pragma unroll
        for (int i = 0; i < 4; ++i) {
            int o  = (i * 512 + tid) * 16;
            int so = o ^ (((o >> 9) & 7) << 4);
            gload16(ga + so, la + o);
            gload16(gb + so, lb + o);
        }
    }
    __syncthreads();

    const int lane = tid & 63;
    const int w  = tid >> 6;                  // 0..7
    const int wm = (w >> 1) * 16;             // 0,16,32,48
    const int wn = (w & 1) * 32;              // 0,32
    const int r  = lane & 15, kb = lane >> 4;
    const int r4 = (lane >> 4) * 4, cc = lane & 15;
    const char* la = (const char*)As;

    for (int nb = nb0; nb < nb1; ++nb) {
        int cur = (nb - nb0) & 1;
        if (nb + 1 < nb1) {                   // prefetch next panel
            const char* gb = (const char*)(Bt + (size_t)(nb + 1) * 16384);
            char* lb = (char*)Bs[cur ^ 1];
#pragma unroll
            for (int i = 0; i < 4; ++i) {
                int o  = (i * 512 + tid) * 16;
                int so = o ^ (((o >> 9) & 7) << 4);
                gload16(gb + so, lb + o);
            }
        }
        const char* lb = (const char*)Bs[cur];
        f32x4 acc[2] = {};
#pragma unroll
        for (int ks = 0; ks < 8; ++ks) {
            int row = wm + r;
            int c16 = (ks * 4 + kb) ^ (row & 7);
            s16x8 af = *(const s16x8*)(la + row * 512 + c16 * 16);
#pragma unroll
            for (int j = 0; j < 2; ++j) {
                int col = wn + j * 16 + r;
                int d16 = (ks * 4 + kb) ^ (col & 7);
                s16x8 bfr = *(const s16x8*)(lb + col * 512 + d16 * 16);
                acc[j] = __builtin_amdgcn_mfma_f32_16x16x32_bf16(af, bfr, acc[j], 0, 0, 0);
            }
        }
        // epilogue for this panel
#pragma unroll
        for (int j = 0; j < 2; ++j) {
            int col = nb * 64 + wn + j * 16 + cc;
#pragma unroll
            for (int q = 0; q < 4; ++q) {
                int row = bm + wm + r4 + q;
                float v = acc[j][q];
                if (Cb) {
                    if (col < 256) {
                        Cb[(size_t)row * 256 + col] = f2bf(v);
                    } else if (col < 264) {
                        sbuf[(size_t)row * 8 + (col - 256)] = v;
                    } else if (col < 272) {
                        tbuf[(size_t)row * 8 + (col - 264)] = v;
                    }
                } else if (row < M) {
                    Cf[(size_t)row * ldc + col] = v + bias[col];
                }
            }
        }
        __syncthreads();
    }
}

// ------ fused: per-(node,head) softmax + gather-aggregate + bias/relu/residual (bf16 h) ------
__global__ __launch_bounds__(256) void k_fagg(const unsigned short* __restrict__ h1,
                                              const float* __restrict__ sbuf,
                                              const float* __restrict__ tbuf,
                                              const int* __restrict__ rowptr,
                                              const int* __restrict__ srcs,
                                              unsigned short* __restrict__ hbf,
                                              const float* __restrict__ bias, int n) {
    int wave = threadIdx.x >> 6, lane = threadIdx.x & 63;
    int node = blockIdx.x * 4 + wave;
    if (node >= n) return;
    int p0 = rowptr[node], p1 = rowptr[node + 1];
    int head = lane >> 3;
    float tv = tbuf[node * 8 + head];
    // pass 1: max over raw s (leaky-relu monotone -> fold tv+lrelu once), unroll 4
    float m = -1e30f;
    int p = p0;
    for (; p + 3 < p1; p += 4) {
        float e0 = sbuf[srcs[p]     * 8 + head];
        float e1 = sbuf[srcs[p + 1] * 8 + head];
        float e2 = sbuf[srcs[p + 2] * 8 + head];
        float e3 = sbuf[srcs[p + 3] * 8 + head];
        m = fmaxf(m, fmaxf(fmaxf(e0, e1), fmaxf(e2, e3)));
    }
    for (; p < p1; ++p) m = fmaxf(m, sbuf[srcs[p] * 8 + head]);
    m += tv;
    m = (m > 0.f) ? m : 0.2f * m;
    // pass 2: gather with fused numerator+denominator, 4 independent chains
    float den = 1e-16f;
    float a0 = 0.f, a1 = 0.f, a2 = 0.f, a3 = 0.f;
    float c0 = 0.f, c1 = 0.f, c2 = 0.f, c3 = 0.f;
    float d0 = 0.f, d1 = 0.f, d2 = 0.f, d3 = 0.f;
    float g0 = 0.f, g1 = 0.f, g2 = 0.f, g3 = 0.f;
    p = p0;
    for (; p + 3 < p1; p += 4) {
        int s0 = srcs[p], s1 = srcs[p + 1], s2 = srcs[p + 2], s3 = srcs[p + 3];
        float e0 = sbuf[s0 * 8 + head] + tv;
        float e1 = sbuf[s1 * 8 + head] + tv;
        float e2 = sbuf[s2 * 8 + head] + tv;
        float e3 = sbuf[s3 * 8 + head] + tv;
        e0 = (e0 > 0.f) ? e0 : 0.2f * e0;
        e1 = (e1 > 0.f) ? e1 : 0.2f * e1;
        e2 = (e2 > 0.f) ? e2 : 0.2f * e2;
        e3 = (e3 > 0.f) ? e3 : 0.2f * e3;
        float w0 = __expf(e0 - m), w1 = __expf(e1 - m);
        float w2 = __expf(e2 - m), w3 = __expf(e3 - m);
        ushort4 v0 = reinterpret_cast<const ushort4*>(h1 + (size_t)s0 * 256)[lane];
        ushort4 v1 = reinterpret_cast<const ushort4*>(h1 + (size_t)s1 * 256)[lane];
        ushort4 v2 = reinterpret_cast<const ushort4*>(h1 + (size_t)s2 * 256)[lane];
        ushort4 v3 = reinterpret_cast<const ushort4*>(h1 + (size_t)s3 * 256)[lane];
        den += (w0 + w1) + (w2 + w3);
        a0 += w0 * bf2f(v0.x); a1 += w0 * bf2f(v0.y);
        a2 += w0 * bf2f(v0.z); a3 += w0 * bf2f(v0.w);
        c0 += w1 * bf2f(v1.x); c1 += w1 * bf2f(v1.y);
        c2 += w1 * bf2f(v1.z); c3 += w1 * bf2f(v1.w);
        d0 += w2 * bf2f(v2.x); d1 += w2 * bf2f(v2.y);
        d2 += w2 * bf2f(v2.z); d3 += w2 * bf2f(v2.w);
        g0 += w3 * bf2f(v3.x); g1 += w3 * bf2f(v3.y);
        g2 += w3 * bf2f(v3.z); g3 += w3 * bf2f(v3.w);
    }
    for (; p < p1; ++p) {
        int s0 = srcs[p];
        float e0 = sbuf[s0 * 8 + head] + tv;
        e0 = (e0 > 0.f) ? e0 : 0.2f * e0;
        float w0 = __expf(e0 - m);
        ushort4 v0 = reinterpret_cast<const ushort4*>(h1 + (size_t)s0 * 256)[lane];
        den += w0;
        a0 += w0 * bf2f(v0.x); a1 += w0 * bf2f(v0.y);
        a2 += w0 * bf2f(v0.z); a3 += w0 * bf2f(v0.w);
    }
    float inv = 1.0f / den;
    a0 = ((a0 + c0) + (d0 + g0)) * inv;
    a1 = ((a1 + c1) + (d1 + g1)) * inv;
    a2 = ((a2 + c2) + (d2 + g2)) * inv;
    a3 = ((a3 + c3) + (d3 + g3)) * inv;
    float b0_ = 0.f, b1_ = 0.f, b2_ = 0.f, b3_ = 0.f;
    if (bias) {
        float4 bb = reinterpret_cast<const float4*>(bias)[lane];
        b0_ = bb.x; b1_ = bb.y; b2_ = bb.z; b3_ = bb.w;
    }
    size_t base = (size_t)node * 256 + lane * 4;
    ushort4 hv = *reinterpret_cast<const ushort4*>(hbf + base);
    ushort4 o;
    o.x = f2bf(bf2f(hv.x) + fmaxf(a0 + b0_, 0.f));
    o.y = f2bf(bf2f(hv.y) + fmaxf(a1 + b1_, 0.f));
    o.z = f2bf(bf2f(hv.z) + fmaxf(a2 + b2_, 0.f));
    o.w = f2bf(bf2f(hv.w) + fmaxf(a3 + b3_, 0.f));
    *reinterpret_cast<ushort4*>(hbf + base) = o;
}

// ---------------- launch ----------------
extern "C" void kernel_launch(void* const* d_in, const int* in_sizes, int n_in,
                              void* d_out, int out_size, void* d_ws, size_t ws_size,
                              hipStream_t stream) {
    const float* x        = (const float*)d_in[0];
    const float* W0       = (const float*)d_in[1];
    const float* b0       = (const float*)d_in[2];
    const float* gat_lin  = (const float*)d_in[3];
    const float* att_src  = (const float*)d_in[4];
    const float* att_dst  = (const float*)d_in[5];
    const float* gat_bias = (const float*)d_in[6];
    const float* gn_w     = (const float*)d_in[7];
    const float* gn_b     = (const float*)d_in[8];
    const float* gn_ms    = (const float*)d_in[9];
    const float* lin_W    = (const float*)d_in[10];
    const float* lin_b    = (const float*)d_in[11];
    const int*   ei       = (const int*)d_in[12];

    const int n  = in_sizes[0];          // 20000
    const int E  = in_sizes[12] / 2;     // 160000
    const int EP = E + n;                // 180000
    const int Mpad = ((n + BM - 1) / BM) * BM;   // 20032
    const int nb = (n + 255) / 256;      // scan blocks (79)

    // workspace layout (16B-aligned chunks)
    char* w = (char*)d_ws;
    unsigned short* hbf = (unsigned short*)w; w += (size_t)Mpad * 256 * 2;
    unsigned short* h1  = (unsigned short*)w; w += (size_t)Mpad * 256 * 2;
    float* sbuf = (float*)w;                  w += (size_t)Mpad * 8 * 4;
    float* tbuf = (float*)w;                  w += (size_t)Mpad * 8 * 4;
    unsigned short* Wt = (unsigned short*)w;  w += (size_t)5 * 320 * 256 * 2;
    unsigned short* lt = (unsigned short*)w;  w += (size_t)128 * 256 * 2;
    float* gnstat = (float*)w;                w += 1024 * 4;
    float* dinv = (float*)w;                  w += (size_t)n * 4;
    int* deg    = (int*)w;                    w += (size_t)n * 4;
    int* rowptr = (int*)w;                    w += ((size_t)(n + 1) * 4 + 15) / 16 * 16;
    int* wo     = (int*)w;                    w += (size_t)n * 4;
    int* bsum   = (int*)w;                    w += ((size_t)nb * 4 + 15) / 16 * 16;
    int* boff   = (int*)w;                    w += ((size_t)nb * 4 + 15) / 16 * 16;
    int* srcs   = (int*)w;                    w += (size_t)EP * 4;

    const int B256 = 256;
    auto cdiv = [](int a, int b) { return (a + b - 1) / b; };

    hipMemsetAsync(gnstat, 0, 1024 * 4, stream);

    // weight prep
    const int WPREP = 5 * 65536 + 128 * 256 + 5 * 64 * 256;
    k_wprep<<<cdiv(WPREP, B256), B256, 0, stream>>>(gat_lin, lin_W, att_src, att_dst, Wt, lt);

    // graph build (parallel two-level scan)
    k_init_deg<<<cdiv(n, B256), B256, 0, stream>>>(deg, n);
    k_count<<<cdiv(E, B256), B256, 0, stream>>>(ei, E, deg);
    k_bsum<<<nb, 256, 0, stream>>>(deg, bsum, n);
    k_scanb<<<1, 256, 0, stream>>>(bsum, boff, nb);
    k_emit<<<nb, 256, 0, stream>>>(deg, boff, rowptr, wo, dinv, n);
    k_fill<<<cdiv(EP, B256), B256, 0, stream>>>(ei, E, n, wo, srcs);

    // GCN layer (rank-1, fused)
    k_h0f<<<Mpad, 256, 0, stream>>>(x, dinv, rowptr, srcs, W0, b0, hbf, n);

    const float ninv = 1.0f / (float)n;
    const int gx = Mpad / BM;   // 313

    for (int i = 0; i < 5; ++i) {
        if (i % 3 == 0) {
            int g = i / 3;
            k_gn_reduce<<<256, 256, 0, stream>>>(hbf, gnstat + g * 512,
                                                 gnstat + g * 512 + 256, n);
            k_gn_apply<<<n, 256, 0, stream>>>(hbf, gnstat + g * 512,
                                              gn_w + g * 256, gn_b + g * 256,
                                              gn_ms + g * 256, ninv);
        }
        // N=320 in 5 panels, split 3+2 across grid.y
        k_gemm_mfma<<<dim3(gx, 2), 512, 0, stream>>>(
            hbf, Wt + (size_t)i * 81920, h1, nullptr, sbuf, tbuf, nullptr, n, 256, 5, 3);
        k_fagg<<<cdiv(n, 4), 256, 0, stream>>>(
            h1, sbuf, tbuf, rowptr, srcs, hbf,
            (i % 3 == 0) ? gat_bias + i * 256 : nullptr, n);
    }

    // final linear -> d_out (fp32, guarded, +bias), N=128 in 2 panels
    k_gemm_mfma<<<dim3(gx, 1), 512, 0, stream>>>(
        hbf, lt, nullptr, (float*)d_out, nullptr, nullptr, lin_b, n, 128, 2, 2);
}

// Round 7
// 309.143 us; speedup vs baseline: 1.6318x; 1.1321x over previous
//
#include <hip/hip_runtime.h>
#include <hip/hip_bf16.h>
#include <stdint.h>

typedef float f32x4 __attribute__((ext_vector_type(4)));
typedef short s16x8 __attribute__((ext_vector_type(8)));

__device__ __forceinline__ float bf2f(unsigned short u) {
    union { unsigned int i; float f; } v; v.i = ((unsigned int)u) << 16; return v.f;
}
__device__ __forceinline__ unsigned short f2bf(float f) {
    union { float f; unsigned int i; } v; v.f = f;
    unsigned int x = v.i;
    return (unsigned short)((x + 0x7fffu + ((x >> 16) & 1u)) >> 16);
}
__device__ __forceinline__ void gload16(const void* g, void* l) {
    __builtin_amdgcn_global_load_lds(
        (const __attribute__((address_space(1))) void*)g,
        (__attribute__((address_space(3))) void*)l, 16, 0, 0);
}

// ---------------- graph build ----------------
// deg[] pre-zeroed by memset; self-loop handled as +1 in bsum/emit.
__global__ void k_count(const int* __restrict__ ei, int E, int* deg) {
    int e = blockIdx.x * blockDim.x + threadIdx.x;
    if (e < E) atomicAdd(&deg[ei[E + e]], 1);
}

__global__ __launch_bounds__(256) void k_bsum(const int* __restrict__ deg,
                                              int* __restrict__ bsum, int n) {
    __shared__ int buf[256];
    int i = blockIdx.x * 256 + threadIdx.x;
    buf[threadIdx.x] = (i < n) ? deg[i] + 1 : 0;
    __syncthreads();
#pragma unroll
    for (int off = 128; off > 0; off >>= 1) {
        if ((int)threadIdx.x < off) buf[threadIdx.x] += buf[threadIdx.x + off];
        __syncthreads();
    }
    if (threadIdx.x == 0) bsum[blockIdx.x] = buf[0];
}

__global__ __launch_bounds__(256) void k_scanb(const int* __restrict__ bsum,
                                               int* __restrict__ boff, int nb) {
    __shared__ int buf[256];
    int t = threadIdx.x;
    int v = (t < nb) ? bsum[t] : 0;
    buf[t] = v;
    __syncthreads();
    for (int off = 1; off < 256; off <<= 1) {
        int add = (t >= off) ? buf[t - off] : 0;
        __syncthreads();
        buf[t] += add;
        __syncthreads();
    }
    if (t < nb) boff[t] = buf[t] - v;   // exclusive
}

__global__ __launch_bounds__(256) void k_emit(const int* __restrict__ deg,
                                              const int* __restrict__ boff,
                                              int* __restrict__ rowptr,
                                              int* __restrict__ wo,
                                              float* __restrict__ dinv, int n) {
    __shared__ int buf[256];
    int i = blockIdx.x * 256 + threadIdx.x;
    int v = (i < n) ? deg[i] + 1 : 0;
    buf[threadIdx.x] = v;
    __syncthreads();
    for (int off = 1; off < 256; off <<= 1) {
        int add = ((int)threadIdx.x >= off) ? buf[threadIdx.x - off] : 0;
        __syncthreads();
        buf[threadIdx.x] += add;
        __syncthreads();
    }
    if (i < n) {
        int excl = boff[blockIdx.x] + buf[threadIdx.x] - v;
        rowptr[i] = excl;
        wo[i] = excl;
        dinv[i] = rsqrtf((float)v);
        if (i == n - 1) rowptr[n] = excl + v;
    }
}

__global__ void k_fill(const int* __restrict__ ei, int E, int n,
                       int* wo, int* srcs) {
    int e = blockIdx.x * blockDim.x + threadIdx.x;
    int EP = E + n;
    if (e >= EP) return;
    int s_, d_;
    if (e < E) { s_ = ei[e]; d_ = ei[E + e]; }
    else       { s_ = d_ = e - E; }
    int pos = atomicAdd(&wo[d_], 1);
    srcs[pos] = s_;
}

// ---------------- GCN (rank-1): wave per node ----------------
__global__ __launch_bounds__(256) void k_h0f(const float* __restrict__ x,
                                             const float* __restrict__ dinv,
                                             const int* __restrict__ rowptr,
                                             const int* __restrict__ srcs,
                                             const float* __restrict__ W0,
                                             const float* __restrict__ b0,
                                             unsigned short* __restrict__ hbf,
                                             int n, int Mpad) {
    int wave = threadIdx.x >> 6, lane = threadIdx.x & 63;
    int node = blockIdx.x * 4 + wave;
    if (node >= Mpad) return;
    size_t base = (size_t)node * 256 + lane * 4;
    if (node >= n) {
        ushort4 z = {0, 0, 0, 0};
        *reinterpret_cast<ushort4*>(hbf + base) = z;
        return;
    }
    int p0 = rowptr[node], p1 = rowptr[node + 1];
    float sum = 0.f;
    for (int p = p0 + lane; p < p1; p += 64) {
        int s = srcs[p];
        sum += x[s] * dinv[s];
    }
#pragma unroll
    for (int m = 1; m < 64; m <<= 1) sum += __shfl_xor(sum, m);
    float sv = sum * dinv[node];
    float4 wv = *reinterpret_cast<const float4*>(W0 + lane * 4);
    float4 bv = *reinterpret_cast<const float4*>(b0 + lane * 4);
    ushort4 o;
    o.x = f2bf(fmaxf(sv * wv.x + bv.x, 0.f));
    o.y = f2bf(fmaxf(sv * wv.y + bv.y, 0.f));
    o.z = f2bf(fmaxf(sv * wv.z + bv.z, 0.f));
    o.w = f2bf(fmaxf(sv * wv.w + bv.w, 0.f));
    *reinterpret_cast<ushort4*>(hbf + base) = o;
}

// ---------------- weight prep (single kernel) ----------------
// Wt per layer: 320 rows x 256 cols bf16. rows 0..255 = W^T;
// rows 256..263 = W@a_src[head]; 264..271 = W@a_dst[head]; 272..319 = 0.
// lt: 128 rows x 256 cols = lin_W^T.
__global__ void k_wprep(const float* __restrict__ gat_lin,
                        const float* __restrict__ lin_W,
                        const float* __restrict__ att_src,
                        const float* __restrict__ att_dst,
                        unsigned short* __restrict__ Wt,
                        unsigned short* __restrict__ lt) {
    int idx = blockIdx.x * blockDim.x + threadIdx.x;
    const int T1 = 5 * 65536;            // W^T entries
    const int T2 = T1 + 128 * 256;       // + lt entries
    const int T3 = T2 + 5 * 64 * 256;    // + extra rows
    if (idx < T1) {
        int l = idx >> 16, r = idx & 0xFFFF;
        int nrow = r >> 8, k = r & 255;
        Wt[(size_t)l * 81920 + nrow * 256 + k] =
            f2bf(gat_lin[(size_t)l * 65536 + k * 256 + nrow]);
    } else if (idx < T2) {
        int j = idx - T1;
        int nrow = j >> 8, k = j & 255;
        lt[nrow * 256 + k] = f2bf(lin_W[(size_t)k * 128 + nrow]);
    } else if (idx < T3) {
        int j = idx - T2;
        int l = j >> 14, r = j & 16383;
        int row = r >> 8, k = r & 255;
        float v = 0.f;
        if (row < 16) {
            int head = row & 7;
            const float* a = (row < 8) ? (att_src + l * 256 + head * 32)
                                       : (att_dst + l * 256 + head * 32);
            const float* wr = gat_lin + (size_t)l * 65536 + k * 256 + head * 32;
#pragma unroll
            for (int d = 0; d < 32; ++d) v += wr[d] * a[d];
        }
        Wt[(size_t)l * 81920 + (256 + row) * 256 + k] = f2bf(v);
    }
}

// ---------------- GraphNorm: stats reduce (bf16 stream) ----------------
__global__ __launch_bounds__(256) void k_gn_reduce(const unsigned short* __restrict__ hbf,
                                                   float* sums, float* sumsq, int n) {
    int f = threadIdx.x;
    float s = 0.f, q = 0.f;
    for (int r = blockIdx.x; r < n; r += gridDim.x) {
        float v = bf2f(hbf[(size_t)r * 256 + f]);
        s += v; q += v * v;
    }
    atomicAdd(&sums[f], s);
    atomicAdd(&sumsq[f], q);
}

// ---------------- GN fold: Wt <- diag(scale)*Wt, rowbias = off@Wt, export (s,o) ----------------
__global__ __launch_bounds__(256) void k_gnfold(const float* __restrict__ st,
                                                const float* __restrict__ w,
                                                const float* __restrict__ b,
                                                const float* __restrict__ ms,
                                                unsigned short* __restrict__ Wt,
                                                float* __restrict__ so,
                                                float* __restrict__ rowbias,
                                                float ninv) {
    __shared__ float red[256];
    int col = blockIdx.x, k = threadIdx.x;
    float mean = st[k] * ninv;
    float m2   = st[256 + k] * ninv;
    float msf  = ms[k];
    float var  = m2 + msf * mean * mean * (msf - 2.0f);
    float sc = w[k] * rsqrtf(var + 1e-5f);
    float of = b[k] - msf * mean * sc;
    size_t idx = (size_t)col * 256 + k;
    float wv = bf2f(Wt[idx]);
    red[k] = of * wv;
    __syncthreads();
#pragma unroll
    for (int off = 128; off > 0; off >>= 1) {
        if (k < off) red[k] += red[k + off];
        __syncthreads();
    }
    if (k == 0) rowbias[col] = red[0];
    Wt[idx] = f2bf(sc * wv);
    if (col == 0) { so[k] = sc; so[256 + k] = of; }
}

// ---------------- MFMA GEMM with A-reuse: C[M,*] = A[M,256] @ Bt[*,256]^T ----------------
#define BM 64
__global__ __launch_bounds__(512) void k_gemm_mfma(
    const unsigned short* __restrict__ A,
    const unsigned short* __restrict__ Bt,
    unsigned short* __restrict__ Cb,
    float* __restrict__ Cf,
    float* __restrict__ sbuf,
    float* __restrict__ tbuf,
    const float* __restrict__ bias,
    const float* __restrict__ rowbias,
    int M, int ldc, int nbTot, int nbPerY)
{
    __shared__ unsigned short As[64 * 256];        // 32 KB
    __shared__ unsigned short Bs[2][64 * 256];     // 64 KB
    const int tid = threadIdx.x;
    const int bm = blockIdx.x * BM;
    const int nb0 = blockIdx.y * nbPerY;
    int nb1 = nb0 + nbPerY; if (nb1 > nbTot) nb1 = nbTot;

    {   // stage A (32 KB) + first B panel (32 KB)
        const char* ga = (const char*)(A + (size_t)bm * 256);
        const char* gb = (const char*)(Bt + (size_t)nb0 * 16384);
        char* la = (char*)As;
        char* lb = (char*)Bs[0];
#pragma unroll
        for (int i = 0; i < 4; ++i) {
            int o  = (i * 512 + tid) * 16;
            int so = o ^ (((o >> 9) & 7) << 4);
            gload16(ga + so, la + o);
            gload16(gb + so, lb + o);
        }
    }
    __syncthreads();

    const int lane = tid & 63;
    const int w  = tid >> 6;                  // 0..7
    const int wm = (w >> 1) * 16;             // 0,16,32,48
    const int wn = (w & 1) * 32;              // 0,32
    const int r  = lane & 15, kb = lane >> 4;
    const int r4 = (lane >> 4) * 4, cc = lane & 15;
    const char* la = (const char*)As;

    for (int nb = nb0; nb < nb1; ++nb) {
        int cur = (nb - nb0) & 1;
        if (nb + 1 < nb1) {                   // prefetch next panel
            const char* gb = (const char*)(Bt + (size_t)(nb + 1) * 16384);
            char* lb = (char*)Bs[cur ^ 1];
#pragma unroll
            for (int i = 0; i < 4; ++i) {
                int o  = (i * 512 + tid) * 16;
                int so = o ^ (((o >> 9) & 7) << 4);
                gload16(gb + so, lb + o);
            }
        }
        const char* lb = (const char*)Bs[cur];
        f32x4 acc[2] = {};
#pragma unroll
        for (int ks = 0; ks < 8; ++ks) {
            int row = wm + r;
            int c16 = (ks * 4 + kb) ^ (row & 7);
            s16x8 af = *(const s16x8*)(la + row * 512 + c16 * 16);
#pragma unroll
            for (int j = 0; j < 2; ++j) {
                int col = wn + j * 16 + r;
                int d16 = (ks * 4 + kb) ^ (col & 7);
                s16x8 bfr = *(const s16x8*)(lb + col * 512 + d16 * 16);
                acc[j] = __builtin_amdgcn_mfma_f32_16x16x32_bf16(af, bfr, acc[j], 0, 0, 0);
            }
        }
        // epilogue for this panel
#pragma unroll
        for (int j = 0; j < 2; ++j) {
            int col = nb * 64 + wn + j * 16 + cc;
            float rb = rowbias ? rowbias[col] : 0.f;
#pragma unroll
            for (int q = 0; q < 4; ++q) {
                int row = bm + wm + r4 + q;
                float v = acc[j][q] + rb;
                if (Cb) {
                    if (col < 256) {
                        Cb[(size_t)row * 256 + col] = f2bf(v);
                    } else if (col < 264) {
                        sbuf[(size_t)row * 8 + (col - 256)] = v;
                    } else if (col < 272) {
                        tbuf[(size_t)row * 8 + (col - 264)] = v;
                    }
                } else if (row < M) {
                    Cf[(size_t)row * ldc + col] = v + bias[col];
                }
            }
        }
        __syncthreads();
    }
}

// ------ fused: per-(node,head) SINGLE-PASS online softmax + gather + bias/relu/residual ------
// Optional so = [scale(256), off(256)]: residual h is GN'd on the fly (GN fold).
__global__ __launch_bounds__(256) void k_fagg(const unsigned short* __restrict__ h1,
                                              const float* __restrict__ sbuf,
                                              const float* __restrict__ tbuf,
                                              const int* __restrict__ rowptr,
                                              const int* __restrict__ srcs,
                                              unsigned short* __restrict__ hbf,
                                              const float* __restrict__ bias,
                                              const float* __restrict__ so, int n) {
    int wave = threadIdx.x >> 6, lane = threadIdx.x & 63;
    int node = blockIdx.x * 4 + wave;
    if (node >= n) return;
    int p0 = rowptr[node], p1 = rowptr[node + 1];
    int head = lane >> 3;
    float tv = tbuf[node * 8 + head];
    float m = -1e30f, den = 0.f;
    float a0 = 0.f, a1 = 0.f, a2 = 0.f, a3 = 0.f;
    int p = p0;
    for (; p + 3 < p1; p += 4) {
        int s0 = srcs[p], s1 = srcs[p + 1], s2 = srcs[p + 2], s3 = srcs[p + 3];
        float e0 = sbuf[s0 * 8 + head] + tv;
        float e1 = sbuf[s1 * 8 + head] + tv;
        float e2 = sbuf[s2 * 8 + head] + tv;
        float e3 = sbuf[s3 * 8 + head] + tv;
        ushort4 v0 = reinterpret_cast<const ushort4*>(h1 + (size_t)s0 * 256)[lane];
        ushort4 v1 = reinterpret_cast<const ushort4*>(h1 + (size_t)s1 * 256)[lane];
        ushort4 v2 = reinterpret_cast<const ushort4*>(h1 + (size_t)s2 * 256)[lane];
        ushort4 v3 = reinterpret_cast<const ushort4*>(h1 + (size_t)s3 * 256)[lane];
        e0 = (e0 > 0.f) ? e0 : 0.2f * e0;
        e1 = (e1 > 0.f) ? e1 : 0.2f * e1;
        e2 = (e2 > 0.f) ? e2 : 0.2f * e2;
        e3 = (e3 > 0.f) ? e3 : 0.2f * e3;
        float em = fmaxf(fmaxf(e0, e1), fmaxf(e2, e3));
        float mn = fmaxf(m, em);
        float sc = __expf(m - mn);
        float w0 = __expf(e0 - mn), w1 = __expf(e1 - mn);
        float w2 = __expf(e2 - mn), w3 = __expf(e3 - mn);
        den = den * sc + ((w0 + w1) + (w2 + w3));
        a0 = fmaf(a0, sc, w0 * bf2f(v0.x) + w1 * bf2f(v1.x) + w2 * bf2f(v2.x) + w3 * bf2f(v3.x));
        a1 = fmaf(a1, sc, w0 * bf2f(v0.y) + w1 * bf2f(v1.y) + w2 * bf2f(v2.y) + w3 * bf2f(v3.y));
        a2 = fmaf(a2, sc, w0 * bf2f(v0.z) + w1 * bf2f(v1.z) + w2 * bf2f(v2.z) + w3 * bf2f(v3.z));
        a3 = fmaf(a3, sc, w0 * bf2f(v0.w) + w1 * bf2f(v1.w) + w2 * bf2f(v2.w) + w3 * bf2f(v3.w));
        m = mn;
    }
    for (; p < p1; ++p) {
        int s0 = srcs[p];
        float e0 = sbuf[s0 * 8 + head] + tv;
        e0 = (e0 > 0.f) ? e0 : 0.2f * e0;
        ushort4 v0 = reinterpret_cast<const ushort4*>(h1 + (size_t)s0 * 256)[lane];
        float mn = fmaxf(m, e0);
        float sc = __expf(m - mn);
        float w0 = __expf(e0 - mn);
        den = den * sc + w0;
        a0 = fmaf(a0, sc, w0 * bf2f(v0.x));
        a1 = fmaf(a1, sc, w0 * bf2f(v0.y));
        a2 = fmaf(a2, sc, w0 * bf2f(v0.z));
        a3 = fmaf(a3, sc, w0 * bf2f(v0.w));
        m = mn;
    }
    float inv = 1.0f / (den + 1e-16f);
    a0 *= inv; a1 *= inv; a2 *= inv; a3 *= inv;
    float b0_ = 0.f, b1_ = 0.f, b2_ = 0.f, b3_ = 0.f;
    if (bias) {
        float4 bb = reinterpret_cast<const float4*>(bias)[lane];
        b0_ = bb.x; b1_ = bb.y; b2_ = bb.z; b3_ = bb.w;
    }
    size_t base = (size_t)node * 256 + lane * 4;
    ushort4 hv = *reinterpret_cast<const ushort4*>(hbf + base);
    float h0 = bf2f(hv.x), h1v = bf2f(hv.y), h2 = bf2f(hv.z), h3 = bf2f(hv.w);
    if (so) {   // apply GN affine to residual
        float4 sc4 = reinterpret_cast<const float4*>(so)[lane];
        float4 of4 = reinterpret_cast<const float4*>(so + 256)[lane];
        h0 = h0 * sc4.x + of4.x; h1v = h1v * sc4.y + of4.y;
        h2 = h2 * sc4.z + of4.z; h3 = h3 * sc4.w + of4.w;
    }
    ushort4 o;
    o.x = f2bf(h0  + fmaxf(a0 + b0_, 0.f));
    o.y = f2bf(h1v + fmaxf(a1 + b1_, 0.f));
    o.z = f2bf(h2  + fmaxf(a2 + b2_, 0.f));
    o.w = f2bf(h3  + fmaxf(a3 + b3_, 0.f));
    *reinterpret_cast<ushort4*>(hbf + base) = o;
}

// ---------------- launch ----------------
extern "C" void kernel_launch(void* const* d_in, const int* in_sizes, int n_in,
                              void* d_out, int out_size, void* d_ws, size_t ws_size,
                              hipStream_t stream) {
    const float* x        = (const float*)d_in[0];
    const float* W0       = (const float*)d_in[1];
    const float* b0       = (const float*)d_in[2];
    const float* gat_lin  = (const float*)d_in[3];
    const float* att_src  = (const float*)d_in[4];
    const float* att_dst  = (const float*)d_in[5];
    const float* gat_bias = (const float*)d_in[6];
    const float* gn_w     = (const float*)d_in[7];
    const float* gn_b     = (const float*)d_in[8];
    const float* gn_ms    = (const float*)d_in[9];
    const float* lin_W    = (const float*)d_in[10];
    const float* lin_b    = (const float*)d_in[11];
    const int*   ei       = (const int*)d_in[12];

    const int n  = in_sizes[0];          // 20000
    const int E  = in_sizes[12] / 2;     // 160000
    const int EP = E + n;                // 180000
    const int Mpad = ((n + BM - 1) / BM) * BM;   // 20032
    const int nb = (n + 255) / 256;      // scan blocks (79)

    // workspace layout (16B-aligned chunks)
    char* w = (char*)d_ws;
    unsigned short* hbf = (unsigned short*)w; w += (size_t)Mpad * 256 * 2;
    unsigned short* h1  = (unsigned short*)w; w += (size_t)Mpad * 256 * 2;
    float* sbuf = (float*)w;                  w += (size_t)Mpad * 8 * 4;
    float* tbuf = (float*)w;                  w += (size_t)Mpad * 8 * 4;
    unsigned short* Wt = (unsigned short*)w;  w += (size_t)5 * 320 * 256 * 2;
    unsigned short* lt = (unsigned short*)w;  w += (size_t)128 * 256 * 2;
    float* scaleoff = (float*)w;              w += 1024 * 4;   // 2 groups x (s,o)
    float* rowbias  = (float*)w;              w += 640 * 4;    // 2 groups x 320
    float* gnstat = (float*)w;                w += 1024 * 4;   // zeroed (with deg)
    int* deg    = (int*)w;                    w += (size_t)n * 4;
    float* dinv = (float*)w;                  w += (size_t)n * 4;
    int* rowptr = (int*)w;                    w += ((size_t)(n + 1) * 4 + 15) / 16 * 16;
    int* wo     = (int*)w;                    w += (size_t)n * 4;
    int* bsum   = (int*)w;                    w += ((size_t)nb * 4 + 15) / 16 * 16;
    int* boff   = (int*)w;                    w += ((size_t)nb * 4 + 15) / 16 * 16;
    int* srcs   = (int*)w;                    w += (size_t)EP * 4;

    const int B256 = 256;
    auto cdiv = [](int a, int b) { return (a + b - 1) / b; };

    // zero gnstat + deg in one memset (contiguous)
    hipMemsetAsync(gnstat, 0, 1024 * 4 + (size_t)n * 4, stream);

    // weight prep
    const int WPREP = 5 * 65536 + 128 * 256 + 5 * 64 * 256;
    k_wprep<<<cdiv(WPREP, B256), B256, 0, stream>>>(gat_lin, lin_W, att_src, att_dst, Wt, lt);

    // graph build (parallel two-level scan)
    k_count<<<cdiv(E, B256), B256, 0, stream>>>(ei, E, deg);
    k_bsum<<<nb, 256, 0, stream>>>(deg, bsum, n);
    k_scanb<<<1, 256, 0, stream>>>(bsum, boff, nb);
    k_emit<<<nb, 256, 0, stream>>>(deg, boff, rowptr, wo, dinv, n);
    k_fill<<<cdiv(EP, B256), B256, 0, stream>>>(ei, E, n, wo, srcs);

    // GCN layer (rank-1, wave per node)
    k_h0f<<<cdiv(Mpad, 4), 256, 0, stream>>>(x, dinv, rowptr, srcs, W0, b0, hbf, n, Mpad);

    const float ninv = 1.0f / (float)n;
    const int gx = Mpad / BM;   // 313

    for (int i = 0; i < 5; ++i) {
        const float* rb = nullptr;
        const float* so = nullptr;
        if (i % 3 == 0) {
            int g = i / 3;
            k_gn_reduce<<<256, 256, 0, stream>>>(hbf, gnstat + g * 512,
                                                 gnstat + g * 512 + 256, n);
            k_gnfold<<<320, 256, 0, stream>>>(gnstat + g * 512, gn_w + g * 256,
                                              gn_b + g * 256, gn_ms + g * 256,
                                              Wt + (size_t)i * 81920,
                                              scaleoff + g * 512, rowbias + g * 320, ninv);
            rb = rowbias + g * 320;
            so = scaleoff + g * 512;
        }
        k_gemm_mfma<<<dim3(gx, 2), 512, 0, stream>>>(
            hbf, Wt + (size_t)i * 81920, h1, nullptr, sbuf, tbuf, nullptr, rb,
            n, 256, 5, 3);
        k_fagg<<<cdiv(n, 4), 256, 0, stream>>>(
            h1, sbuf, tbuf, rowptr, srcs, hbf,
            (i % 3 == 0) ? gat_bias + i * 256 : nullptr, so, n);
    }

    // final linear -> d_out (fp32, guarded, +bias), N=128 in 2 panels
    k_gemm_mfma<<<dim3(gx, 1), 512, 0, stream>>>(
        hbf, lt, nullptr, (float*)d_out, nullptr, nullptr, lin_b, nullptr,
        n, 128, 2, 2);
}

// Round 8
// 286.705 us; speedup vs baseline: 1.7595x; 1.0783x over previous
//
#include <hip/hip_runtime.h>
#include <hip/hip_bf16.h>
#include <stdint.h>

typedef float f32x4 __attribute__((ext_vector_type(4)));
typedef short s16x8 __attribute__((ext_vector_type(8)));

__device__ __forceinline__ float bf2f(unsigned short u) {
    union { unsigned int i; float f; } v; v.i = ((unsigned int)u) << 16; return v.f;
}
__device__ __forceinline__ unsigned short f2bf(float f) {
    union { float f; unsigned int i; } v; v.f = f;
    unsigned int x = v.i;
    return (unsigned short)((x + 0x7fffu + ((x >> 16) & 1u)) >> 16);
}
// unpack packed bf16 pair (little-endian: lo = even feat, hi = odd feat)
__device__ __forceinline__ void bfp(unsigned int u, float& lo, float& hi) {
    union { unsigned int i; float f; } a, b;
    a.i = u << 16; b.i = u & 0xffff0000u;
    lo = a.f; hi = b.f;
}
__device__ __forceinline__ void gload16(const void* g, void* l) {
    __builtin_amdgcn_global_load_lds(
        (const __attribute__((address_space(1))) void*)g,
        (__attribute__((address_space(3))) void*)l, 16, 0, 0);
}

// ---------------- graph build ----------------
// deg[] pre-zeroed by memset; self-loop handled as +1 in bsum/emit.
__global__ void k_count(const int* __restrict__ ei, int E, int* deg) {
    int e = blockIdx.x * blockDim.x + threadIdx.x;
    if (e < E) atomicAdd(&deg[ei[E + e]], 1);
}

__global__ __launch_bounds__(256) void k_bsum(const int* __restrict__ deg,
                                              int* __restrict__ bsum, int n) {
    __shared__ int buf[256];
    int i = blockIdx.x * 256 + threadIdx.x;
    buf[threadIdx.x] = (i < n) ? deg[i] + 1 : 0;
    __syncthreads();
#pragma unroll
    for (int off = 128; off > 0; off >>= 1) {
        if ((int)threadIdx.x < off) buf[threadIdx.x] += buf[threadIdx.x + off];
        __syncthreads();
    }
    if (threadIdx.x == 0) bsum[blockIdx.x] = buf[0];
}

__global__ __launch_bounds__(256) void k_scanb(const int* __restrict__ bsum,
                                               int* __restrict__ boff, int nb) {
    __shared__ int buf[256];
    int t = threadIdx.x;
    int v = (t < nb) ? bsum[t] : 0;
    buf[t] = v;
    __syncthreads();
    for (int off = 1; off < 256; off <<= 1) {
        int add = (t >= off) ? buf[t - off] : 0;
        __syncthreads();
        buf[t] += add;
        __syncthreads();
    }
    if (t < nb) boff[t] = buf[t] - v;   // exclusive
}

__global__ __launch_bounds__(256) void k_emit(const int* __restrict__ deg,
                                              const int* __restrict__ boff,
                                              int* __restrict__ rowptr,
                                              int* __restrict__ wo,
                                              float* __restrict__ dinv, int n) {
    __shared__ int buf[256];
    int i = blockIdx.x * 256 + threadIdx.x;
    int v = (i < n) ? deg[i] + 1 : 0;
    buf[threadIdx.x] = v;
    __syncthreads();
    for (int off = 1; off < 256; off <<= 1) {
        int add = ((int)threadIdx.x >= off) ? buf[threadIdx.x - off] : 0;
        __syncthreads();
        buf[threadIdx.x] += add;
        __syncthreads();
    }
    if (i < n) {
        int excl = boff[blockIdx.x] + buf[threadIdx.x] - v;
        rowptr[i] = excl;
        wo[i] = excl;
        dinv[i] = rsqrtf((float)v);
        if (i == n - 1) rowptr[n] = excl + v;
    }
}

__global__ void k_fill(const int* __restrict__ ei, int E, int n,
                       int* wo, int* srcs) {
    int e = blockIdx.x * blockDim.x + threadIdx.x;
    int EP = E + n;
    if (e >= EP) return;
    int s_, d_;
    if (e < E) { s_ = ei[e]; d_ = ei[E + e]; }
    else       { s_ = d_ = e - E; }
    int pos = atomicAdd(&wo[d_], 1);
    srcs[pos] = s_;
}

// ---------------- GCN (rank-1): wave per node ----------------
__global__ __launch_bounds__(256) void k_h0f(const float* __restrict__ x,
                                             const float* __restrict__ dinv,
                                             const int* __restrict__ rowptr,
                                             const int* __restrict__ srcs,
                                             const float* __restrict__ W0,
                                             const float* __restrict__ b0,
                                             unsigned short* __restrict__ hbf,
                                             int n, int Mpad) {
    int wave = threadIdx.x >> 6, lane = threadIdx.x & 63;
    int node = blockIdx.x * 4 + wave;
    if (node >= Mpad) return;
    size_t base = (size_t)node * 256 + lane * 4;
    if (node >= n) {
        ushort4 z = {0, 0, 0, 0};
        *reinterpret_cast<ushort4*>(hbf + base) = z;
        return;
    }
    int p0 = rowptr[node], p1 = rowptr[node + 1];
    float sum = 0.f;
    for (int p = p0 + lane; p < p1; p += 64) {
        int s = srcs[p];
        sum += x[s] * dinv[s];
    }
#pragma unroll
    for (int m = 1; m < 64; m <<= 1) sum += __shfl_xor(sum, m);
    float sv = sum * dinv[node];
    float4 wv = *reinterpret_cast<const float4*>(W0 + lane * 4);
    float4 bv = *reinterpret_cast<const float4*>(b0 + lane * 4);
    ushort4 o;
    o.x = f2bf(fmaxf(sv * wv.x + bv.x, 0.f));
    o.y = f2bf(fmaxf(sv * wv.y + bv.y, 0.f));
    o.z = f2bf(fmaxf(sv * wv.z + bv.z, 0.f));
    o.w = f2bf(fmaxf(sv * wv.w + bv.w, 0.f));
    *reinterpret_cast<ushort4*>(hbf + base) = o;
}

// ---------------- weight prep (single kernel) ----------------
__global__ void k_wprep(const float* __restrict__ gat_lin,
                        const float* __restrict__ lin_W,
                        const float* __restrict__ att_src,
                        const float* __restrict__ att_dst,
                        unsigned short* __restrict__ Wt,
                        unsigned short* __restrict__ lt) {
    int idx = blockIdx.x * blockDim.x + threadIdx.x;
    const int T1 = 5 * 65536;            // W^T entries
    const int T2 = T1 + 128 * 256;       // + lt entries
    const int T3 = T2 + 5 * 64 * 256;    // + extra rows
    if (idx < T1) {
        int l = idx >> 16, r = idx & 0xFFFF;
        int nrow = r >> 8, k = r & 255;
        Wt[(size_t)l * 81920 + nrow * 256 + k] =
            f2bf(gat_lin[(size_t)l * 65536 + k * 256 + nrow]);
    } else if (idx < T2) {
        int j = idx - T1;
        int nrow = j >> 8, k = j & 255;
        lt[nrow * 256 + k] = f2bf(lin_W[(size_t)k * 128 + nrow]);
    } else if (idx < T3) {
        int j = idx - T2;
        int l = j >> 14, r = j & 16383;
        int row = r >> 8, k = r & 255;
        float v = 0.f;
        if (row < 16) {
            int head = row & 7;
            const float* a = (row < 8) ? (att_src + l * 256 + head * 32)
                                       : (att_dst + l * 256 + head * 32);
            const float* wr = gat_lin + (size_t)l * 65536 + k * 256 + head * 32;
#pragma unroll
            for (int d = 0; d < 32; ++d) v += wr[d] * a[d];
        }
        Wt[(size_t)l * 81920 + (256 + row) * 256 + k] = f2bf(v);
    }
}

// ---------------- GraphNorm: stats reduce (bf16 stream) ----------------
__global__ __launch_bounds__(256) void k_gn_reduce(const unsigned short* __restrict__ hbf,
                                                   float* sums, float* sumsq, int n) {
    int f = threadIdx.x;
    float s = 0.f, q = 0.f;
    for (int r = blockIdx.x; r < n; r += gridDim.x) {
        float v = bf2f(hbf[(size_t)r * 256 + f]);
        s += v; q += v * v;
    }
    atomicAdd(&sums[f], s);
    atomicAdd(&sumsq[f], q);
}

// ---------------- GN fold: Wt <- diag(scale)*Wt, rowbias = off@Wt, export (s,o) ----------------
__global__ __launch_bounds__(256) void k_gnfold(const float* __restrict__ st,
                                                const float* __restrict__ w,
                                                const float* __restrict__ b,
                                                const float* __restrict__ ms,
                                                unsigned short* __restrict__ Wt,
                                                float* __restrict__ so,
                                                float* __restrict__ rowbias,
                                                float ninv) {
    __shared__ float red[256];
    int col = blockIdx.x, k = threadIdx.x;
    float mean = st[k] * ninv;
    float m2   = st[256 + k] * ninv;
    float msf  = ms[k];
    float var  = m2 + msf * mean * mean * (msf - 2.0f);
    float sc = w[k] * rsqrtf(var + 1e-5f);
    float of = b[k] - msf * mean * sc;
    size_t idx = (size_t)col * 256 + k;
    float wv = bf2f(Wt[idx]);
    red[k] = of * wv;
    __syncthreads();
#pragma unroll
    for (int off = 128; off > 0; off >>= 1) {
        if (k < off) red[k] += red[k + off];
        __syncthreads();
    }
    if (k == 0) rowbias[col] = red[0];
    Wt[idx] = f2bf(sc * wv);
    if (col == 0) { so[k] = sc; so[256 + k] = of; }
}

// ---------------- MFMA GEMM (single-shot tile): C[64, 64panel] = A[64,256] @ Bt[64,256]^T ----
#define BM 64
__global__ __launch_bounds__(512) void k_gemm_mfma(
    const unsigned short* __restrict__ A,
    const unsigned short* __restrict__ Bt,
    unsigned short* __restrict__ Cb,
    float* __restrict__ Cf,
    float* __restrict__ sbuf,
    float* __restrict__ tbuf,
    const float* __restrict__ bias,
    const float* __restrict__ rowbias,
    int M, int ldc)
{
    __shared__ unsigned short As[64 * 256];        // 32 KB
    __shared__ unsigned short Bs[64 * 256];        // 32 KB
    const int tid = threadIdx.x;
    const int bm = blockIdx.x * BM;
    const int bn = blockIdx.y * 64;
    {   // stage A tile + B panel (64 KB total, 8 x gload16 per thread)
        const char* ga = (const char*)(A + (size_t)bm * 256);
        const char* gb = (const char*)(Bt + (size_t)bn * 256);
        char* la = (char*)As;
        char* lb = (char*)Bs;
#pragma unroll
        for (int i = 0; i < 4; ++i) {
            int o  = (i * 512 + tid) * 16;
            int so = o ^ (((o >> 9) & 7) << 4);
            gload16(ga + so, la + o);
            gload16(gb + so, lb + o);
        }
    }
    __syncthreads();

    const int lane = tid & 63;
    const int w  = tid >> 6;                  // 0..7
    const int wm = (w >> 1) * 16;             // 0,16,32,48
    const int wn = (w & 1) * 32;              // 0,32
    const int r  = lane & 15, kb = lane >> 4;
    const int r4 = (lane >> 4) * 4, cc = lane & 15;
    const char* la = (const char*)As;
    const char* lb = (const char*)Bs;

    f32x4 acc[2] = {};
#pragma unroll
    for (int ks = 0; ks < 8; ++ks) {
        int row = wm + r;
        int c16 = (ks * 4 + kb) ^ (row & 7);
        s16x8 af = *(const s16x8*)(la + row * 512 + c16 * 16);
#pragma unroll
        for (int j = 0; j < 2; ++j) {
            int col = wn + j * 16 + r;
            int d16 = (ks * 4 + kb) ^ (col & 7);
            s16x8 bfr = *(const s16x8*)(lb + col * 512 + d16 * 16);
            acc[j] = __builtin_amdgcn_mfma_f32_16x16x32_bf16(af, bfr, acc[j], 0, 0, 0);
        }
    }
#pragma unroll
    for (int j = 0; j < 2; ++j) {
        int col = bn + wn + j * 16 + cc;
        float rb = rowbias ? rowbias[col] : 0.f;
#pragma unroll
        for (int q = 0; q < 4; ++q) {
            int row = bm + wm + r4 + q;
            float v = acc[j][q] + rb;
            if (Cb) {
                if (col < 256) {
                    Cb[(size_t)row * 256 + col] = f2bf(v);
                } else if (col < 264) {
                    sbuf[(size_t)row * 8 + (col - 256)] = v;
                } else if (col < 272) {
                    tbuf[(size_t)row * 8 + (col - 264)] = v;
                }
            } else if (row < M) {
                Cf[(size_t)row * ldc + col] = v + bias[col];
            }
        }
    }
}

// ------ fused: half-wave-parallel online softmax + gather + bias/relu/residual ------
// Wave = 1 node. Lanes 0-31 process even edges, 32-63 odd edges; lane owns 8 features.
// Optional so = [scale(256), off(256)]: residual h is GN'd on the fly (GN fold).
__global__ __launch_bounds__(256) void k_fagg(const unsigned short* __restrict__ h1,
                                              const float* __restrict__ sbuf,
                                              const float* __restrict__ tbuf,
                                              const int* __restrict__ rowptr,
                                              const int* __restrict__ srcs,
                                              unsigned short* __restrict__ hbf,
                                              const float* __restrict__ bias,
                                              const float* __restrict__ so, int n) {
    int wave = threadIdx.x >> 6, lane = threadIdx.x & 63;
    int node = blockIdx.x * 4 + wave;
    if (node >= n) return;
    int p0 = rowptr[node], p1 = rowptr[node + 1];
    int hid = lane >> 5;            // half id
    int l5 = lane & 31;
    int fl = l5 * 8;                // feature base (8 feats/lane)
    int head = l5 >> 2;             // 4 lanes per head
    float tv = tbuf[node * 8 + head];
    float m = -1e30f, den = 0.f;
    float a0 = 0.f, a1 = 0.f, a2 = 0.f, a3 = 0.f;
    float a4 = 0.f, a5 = 0.f, a6 = 0.f, a7 = 0.f;
    int q = p0 + hid;
    // unroll 2: edges q, q+2 (this half's stream)
    for (; q + 2 < p1; q += 4) {
        int s0 = srcs[q], s1 = srcs[q + 2];
        float e0 = sbuf[s0 * 8 + head] + tv;
        float e1 = sbuf[s1 * 8 + head] + tv;
        uint4 v0 = *reinterpret_cast<const uint4*>(h1 + (size_t)s0 * 256 + fl);
        uint4 v1 = *reinterpret_cast<const uint4*>(h1 + (size_t)s1 * 256 + fl);
        e0 = (e0 > 0.f) ? e0 : 0.2f * e0;
        e1 = (e1 > 0.f) ? e1 : 0.2f * e1;
        float mn = fmaxf(m, fmaxf(e0, e1));
        float sc = __expf(m - mn);
        float w0 = __expf(e0 - mn), w1 = __expf(e1 - mn);
        den = den * sc + (w0 + w1);
        float f0l, f0h, f1l, f1h;
        bfp(v0.x, f0l, f0h); bfp(v1.x, f1l, f1h);
        a0 = fmaf(a0, sc, w0 * f0l + w1 * f1l);
        a1 = fmaf(a1, sc, w0 * f0h + w1 * f1h);
        bfp(v0.y, f0l, f0h); bfp(v1.y, f1l, f1h);
        a2 = fmaf(a2, sc, w0 * f0l + w1 * f1l);
        a3 = fmaf(a3, sc, w0 * f0h + w1 * f1h);
        bfp(v0.z, f0l, f0h); bfp(v1.z, f1l, f1h);
        a4 = fmaf(a4, sc, w0 * f0l + w1 * f1l);
        a5 = fmaf(a5, sc, w0 * f0h + w1 * f1h);
        bfp(v0.w, f0l, f0h); bfp(v1.w, f1l, f1h);
        a6 = fmaf(a6, sc, w0 * f0l + w1 * f1l);
        a7 = fmaf(a7, sc, w0 * f0h + w1 * f1h);
        m = mn;
    }
    for (; q < p1; q += 2) {
        int s0 = srcs[q];
        float e0 = sbuf[s0 * 8 + head] + tv;
        uint4 v0 = *reinterpret_cast<const uint4*>(h1 + (size_t)s0 * 256 + fl);
        e0 = (e0 > 0.f) ? e0 : 0.2f * e0;
        float mn = fmaxf(m, e0);
        float sc = __expf(m - mn);
        float w0 = __expf(e0 - mn);
        den = den * sc + w0;
        float f0l, f0h;
        bfp(v0.x, f0l, f0h);
        a0 = fmaf(a0, sc, w0 * f0l); a1 = fmaf(a1, sc, w0 * f0h);
        bfp(v0.y, f0l, f0h);
        a2 = fmaf(a2, sc, w0 * f0l); a3 = fmaf(a3, sc, w0 * f0h);
        bfp(v0.z, f0l, f0h);
        a4 = fmaf(a4, sc, w0 * f0l); a5 = fmaf(a5, sc, w0 * f0h);
        bfp(v0.w, f0l, f0h);
        a6 = fmaf(a6, sc, w0 * f0l); a7 = fmaf(a7, sc, w0 * f0h);
        m = mn;
    }
    // merge the two halves' online-softmax states
    float mo = __shfl_xor(m, 32);
    float mm = fmaxf(m, mo);
    float sc = __expf(m - mm);
    den *= sc; den += __shfl_xor(den, 32);
    a0 *= sc; a0 += __shfl_xor(a0, 32);
    a1 *= sc; a1 += __shfl_xor(a1, 32);
    a2 *= sc; a2 += __shfl_xor(a2, 32);
    a3 *= sc; a3 += __shfl_xor(a3, 32);
    a4 *= sc; a4 += __shfl_xor(a4, 32);
    a5 *= sc; a5 += __shfl_xor(a5, 32);
    a6 *= sc; a6 += __shfl_xor(a6, 32);
    a7 *= sc; a7 += __shfl_xor(a7, 32);
    if (hid) return;     // lanes 0-31 finish the row
    float inv = 1.0f / (den + 1e-16f);
    a0 *= inv; a1 *= inv; a2 *= inv; a3 *= inv;
    a4 *= inv; a5 *= inv; a6 *= inv; a7 *= inv;
    float b_[8] = {0.f, 0.f, 0.f, 0.f, 0.f, 0.f, 0.f, 0.f};
    if (bias) {
        float4 blo = *reinterpret_cast<const float4*>(bias + fl);
        float4 bhi = *reinterpret_cast<const float4*>(bias + fl + 4);
        b_[0] = blo.x; b_[1] = blo.y; b_[2] = blo.z; b_[3] = blo.w;
        b_[4] = bhi.x; b_[5] = bhi.y; b_[6] = bhi.z; b_[7] = bhi.w;
    }
    size_t base = (size_t)node * 256 + fl;
    uint4 hv = *reinterpret_cast<const uint4*>(hbf + base);
    float h_[8];
    bfp(hv.x, h_[0], h_[1]); bfp(hv.y, h_[2], h_[3]);
    bfp(hv.z, h_[4], h_[5]); bfp(hv.w, h_[6], h_[7]);
    if (so) {   // apply GN affine to residual
        float4 s0v = *reinterpret_cast<const float4*>(so + fl);
        float4 s1v = *reinterpret_cast<const float4*>(so + fl + 4);
        float4 o0v = *reinterpret_cast<const float4*>(so + 256 + fl);
        float4 o1v = *reinterpret_cast<const float4*>(so + 256 + fl + 4);
        h_[0] = h_[0] * s0v.x + o0v.x; h_[1] = h_[1] * s0v.y + o0v.y;
        h_[2] = h_[2] * s0v.z + o0v.z; h_[3] = h_[3] * s0v.w + o0v.w;
        h_[4] = h_[4] * s1v.x + o1v.x; h_[5] = h_[5] * s1v.y + o1v.y;
        h_[6] = h_[6] * s1v.z + o1v.z; h_[7] = h_[7] * s1v.w + o1v.w;
    }
    float r0 = h_[0] + fmaxf(a0 + b_[0], 0.f);
    float r1 = h_[1] + fmaxf(a1 + b_[1], 0.f);
    float r2 = h_[2] + fmaxf(a2 + b_[2], 0.f);
    float r3 = h_[3] + fmaxf(a3 + b_[3], 0.f);
    float r4 = h_[4] + fmaxf(a4 + b_[4], 0.f);
    float r5 = h_[5] + fmaxf(a5 + b_[5], 0.f);
    float r6 = h_[6] + fmaxf(a6 + b_[6], 0.f);
    float r7 = h_[7] + fmaxf(a7 + b_[7], 0.f);
    uint4 o;
    o.x = (unsigned int)f2bf(r0) | ((unsigned int)f2bf(r1) << 16);
    o.y = (unsigned int)f2bf(r2) | ((unsigned int)f2bf(r3) << 16);
    o.z = (unsigned int)f2bf(r4) | ((unsigned int)f2bf(r5) << 16);
    o.w = (unsigned int)f2bf(r6) | ((unsigned int)f2bf(r7) << 16);
    *reinterpret_cast<uint4*>(hbf + base) = o;
}

// ---------------- launch ----------------
extern "C" void kernel_launch(void* const* d_in, const int* in_sizes, int n_in,
                              void* d_out, int out_size, void* d_ws, size_t ws_size,
                              hipStream_t stream) {
    const float* x        = (const float*)d_in[0];
    const float* W0       = (const float*)d_in[1];
    const float* b0       = (const float*)d_in[2];
    const float* gat_lin  = (const float*)d_in[3];
    const float* att_src  = (const float*)d_in[4];
    const float* att_dst  = (const float*)d_in[5];
    const float* gat_bias = (const float*)d_in[6];
    const float* gn_w     = (const float*)d_in[7];
    const float* gn_b     = (const float*)d_in[8];
    const float* gn_ms    = (const float*)d_in[9];
    const float* lin_W    = (const float*)d_in[10];
    const float* lin_b    = (const float*)d_in[11];
    const int*   ei       = (const int*)d_in[12];

    const int n  = in_sizes[0];          // 20000
    const int E  = in_sizes[12] / 2;     // 160000
    const int EP = E + n;                // 180000
    const int Mpad = ((n + BM - 1) / BM) * BM;   // 20032
    const int nb = (n + 255) / 256;      // scan blocks (79)

    // workspace layout (16B-aligned chunks)
    char* w = (char*)d_ws;
    unsigned short* hbf = (unsigned short*)w; w += (size_t)Mpad * 256 * 2;
    unsigned short* h1  = (unsigned short*)w; w += (size_t)Mpad * 256 * 2;
    float* sbuf = (float*)w;                  w += (size_t)Mpad * 8 * 4;
    float* tbuf = (float*)w;                  w += (size_t)Mpad * 8 * 4;
    unsigned short* Wt = (unsigned short*)w;  w += (size_t)5 * 320 * 256 * 2;
    unsigned short* lt = (unsigned short*)w;  w += (size_t)128 * 256 * 2;
    float* scaleoff = (float*)w;              w += 1024 * 4;   // 2 groups x (s,o)
    float* rowbias  = (float*)w;              w += 640 * 4;    // 2 groups x 320
    float* gnstat = (float*)w;                w += 1024 * 4;   // zeroed (with deg)
    int* deg    = (int*)w;                    w += (size_t)n * 4;
    float* dinv = (float*)w;                  w += (size_t)n * 4;
    int* rowptr = (int*)w;                    w += ((size_t)(n + 1) * 4 + 15) / 16 * 16;
    int* wo     = (int*)w;                    w += (size_t)n * 4;
    int* bsum   = (int*)w;                    w += ((size_t)nb * 4 + 15) / 16 * 16;
    int* boff   = (int*)w;                    w += ((size_t)nb * 4 + 15) / 16 * 16;
    int* srcs   = (int*)w;                    w += (size_t)EP * 4;

    const int B256 = 256;
    auto cdiv = [](int a, int b) { return (a + b - 1) / b; };

    // zero gnstat + deg in one memset (contiguous)
    hipMemsetAsync(gnstat, 0, 1024 * 4 + (size_t)n * 4, stream);

    // weight prep
    const int WPREP = 5 * 65536 + 128 * 256 + 5 * 64 * 256;
    k_wprep<<<cdiv(WPREP, B256), B256, 0, stream>>>(gat_lin, lin_W, att_src, att_dst, Wt, lt);

    // graph build (parallel two-level scan)
    k_count<<<cdiv(E, B256), B256, 0, stream>>>(ei, E, deg);
    k_bsum<<<nb, 256, 0, stream>>>(deg, bsum, n);
    k_scanb<<<1, 256, 0, stream>>>(bsum, boff, nb);
    k_emit<<<nb, 256, 0, stream>>>(deg, boff, rowptr, wo, dinv, n);
    k_fill<<<cdiv(EP, B256), B256, 0, stream>>>(ei, E, n, wo, srcs);

    // GCN layer (rank-1, wave per node)
    k_h0f<<<cdiv(Mpad, 4), 256, 0, stream>>>(x, dinv, rowptr, srcs, W0, b0, hbf, n, Mpad);

    const float ninv = 1.0f / (float)n;
    const int gx = Mpad / BM;   // 313

    for (int i = 0; i < 5; ++i) {
        const float* rb = nullptr;
        const float* so = nullptr;
        if (i % 3 == 0) {
            int g = i / 3;
            k_gn_reduce<<<256, 256, 0, stream>>>(hbf, gnstat + g * 512,
                                                 gnstat + g * 512 + 256, n);
            k_gnfold<<<320, 256, 0, stream>>>(gnstat + g * 512, gn_w + g * 256,
                                              gn_b + g * 256, gn_ms + g * 256,
                                              Wt + (size_t)i * 81920,
                                              scaleoff + g * 512, rowbias + g * 320, ninv);
            rb = rowbias + g * 320;
            so = scaleoff + g * 512;
        }
        k_gemm_mfma<<<dim3(gx, 5), 512, 0, stream>>>(
            hbf, Wt + (size_t)i * 81920, h1, nullptr, sbuf, tbuf, nullptr, rb,
            n, 256);
        k_fagg<<<cdiv(n, 4), 256, 0, stream>>>(
            h1, sbuf, tbuf, rowptr, srcs, hbf,
            (i % 3 == 0) ? gat_bias + i * 256 : nullptr, so, n);
    }

    // final linear -> d_out (fp32, guarded, +bias), N=128 in 2 panels
    k_gemm_mfma<<<dim3(gx, 2), 512, 0, stream>>>(
        hbf, lt, nullptr, (float*)d_out, nullptr, nullptr, lin_b, nullptr,
        n, 128);
}